// Round 1
// baseline (1737.722 us; speedup 1.0000x reference)
//
#include <hip/hip_runtime.h>
#include <hip/hip_bf16.h>
#include <math.h>

#define N_NODES 50000
#define N_EDGES 800000
#define IN_DIM 128
#define NHEAD 4
#define NREL 64
#define HC 256              // NHEAD * 64 (both layers: H*HID = H*OUT = 256)
#define NEG_SLOPE 0.2f

// -------- helpers --------
__device__ __forceinline__ void atomicMaxFloat(float* addr, float val) {
  // works with initial bit pattern 0xFFFFFFFF (acts as -inf identity)
  if (val >= 0.0f) {
    atomicMax((int*)addr, __float_as_int(val));
  } else {
    atomicMin((unsigned int*)addr, __float_as_uint(val));
  }
}

// -------- GEMM: Y[M x 256] = X[M x K] @ W[K x 256] --------
__global__ __launch_bounds__(256) void gemm_xw(
    const float* __restrict__ X, const float* __restrict__ W,
    float* __restrict__ Y, int M, int K) {
  __shared__ __align__(16) float wlds[32][256];   // [kk][col]
  __shared__ __align__(16) float xlds[32][36];    // [kk][row], padded
  const int t = threadIdx.x;
  const int wv = t >> 6;          // wave id 0..3 -> rows wv*8..wv*8+7
  const int tx = t & 63;          // lane -> cols tx*4..tx*4+3
  const int c4 = tx * 4;
  const int rbase = wv * 8;
  const int row0 = blockIdx.x * 32;

  float acc[8][4];
#pragma unroll
  for (int r = 0; r < 8; ++r)
#pragma unroll
    for (int c = 0; c < 4; ++c) acc[r][c] = 0.f;

  for (int kb = 0; kb < K; kb += 32) {
    __syncthreads();
    // load W tile 32x256 (float4, coalesced)
#pragma unroll
    for (int i = 0; i < 8; ++i) {
      int rr = i * 4 + wv;
      *(float4*)&wlds[rr][c4] = *(const float4*)&W[(size_t)(kb + rr) * HC + c4];
    }
    // load X tile 32 rows x 32 k, store transposed [kk][row]
    {
      int r = t >> 3;
      int kk = (t & 7) * 4;
      int row = row0 + r;
      float4 xv = make_float4(0.f, 0.f, 0.f, 0.f);
      if (row < M) xv = *(const float4*)&X[(size_t)row * K + kb + kk];
      xlds[kk + 0][r] = xv.x;
      xlds[kk + 1][r] = xv.y;
      xlds[kk + 2][r] = xv.z;
      xlds[kk + 3][r] = xv.w;
    }
    __syncthreads();
#pragma unroll
    for (int kk = 0; kk < 32; ++kk) {
      const float4 w4 = *(const float4*)&wlds[kk][c4];
      const float4 xa = *(const float4*)&xlds[kk][rbase];
      const float4 xb = *(const float4*)&xlds[kk][rbase + 4];
      const float xr[8] = {xa.x, xa.y, xa.z, xa.w, xb.x, xb.y, xb.z, xb.w};
#pragma unroll
      for (int r = 0; r < 8; ++r) {
        acc[r][0] += xr[r] * w4.x;
        acc[r][1] += xr[r] * w4.y;
        acc[r][2] += xr[r] * w4.z;
        acc[r][3] += xr[r] * w4.w;
      }
    }
  }
#pragma unroll
  for (int r = 0; r < 8; ++r) {
    int row = row0 + rbase + r;
    if (row < M) {
      float4 o = make_float4(acc[r][0], acc[r][1], acc[r][2], acc[r][3]);
      *(float4*)&Y[(size_t)row * HC + c4] = o;
    }
  }
}

// -------- per-(node,head) attention coefficients --------
__global__ __launch_bounds__(256) void alpha_kernel(
    const float* __restrict__ xs, const float* __restrict__ a_s,
    const float* __restrict__ a_d, float* __restrict__ asrc,
    float* __restrict__ adst) {
  int gw = (blockIdx.x * blockDim.x + threadIdx.x) >> 6;
  int lane = threadIdx.x & 63;
  if (gw >= N_NODES * NHEAD) return;
  int n = gw >> 2, h = gw & 3;
  float v = xs[(size_t)n * HC + h * 64 + lane];
  float s = v * a_s[h * 64 + lane];
  float d = v * a_d[h * 64 + lane];
#pragma unroll
  for (int off = 32; off > 0; off >>= 1) {
    s += __shfl_down(s, off);
    d += __shfl_down(d, off);
  }
  if (lane == 0) {
    asrc[gw] = s;
    adst[gw] = d;
  }
}

// -------- per-relation alpha_e table [R, H] --------
__global__ __launch_bounds__(256) void relalpha_kernel(
    const float* __restrict__ rel, const float* __restrict__ We,
    const float* __restrict__ a_e, float* __restrict__ tab, int K) {
  int r = blockIdx.x;
  int t = threadIdx.x;  // col in [0,256)
  float acc = 0.f;
  for (int k = 0; k < K; ++k) acc += rel[(size_t)r * K + k] * We[(size_t)k * HC + t];
  int h = t >> 6, lane = t & 63;
  float p = acc * a_e[t];
#pragma unroll
  for (int off = 32; off > 0; off >>= 1) p += __shfl_down(p, off);
  if (lane == 0) tab[r * NHEAD + h] = p;
}

// -------- edge pass 1: logits + segment max --------
__global__ __launch_bounds__(256) void edge_logits_kernel(
    const int* __restrict__ src, const int* __restrict__ dst,
    const int* __restrict__ etype, const float* __restrict__ asrc,
    const float* __restrict__ adst, const float* __restrict__ tab,
    float* __restrict__ logits, float* __restrict__ lmax) {
  int g = blockIdx.x * blockDim.x + threadIdx.x;
  if (g >= N_EDGES * NHEAD) return;
  int e = g >> 2, h = g & 3;
  int s = src[e], d = dst[e], r = etype[e];
  float l = asrc[s * NHEAD + h] + adst[d * NHEAD + h] + tab[r * NHEAD + h];
  l = (l >= 0.f) ? l : NEG_SLOPE * l;
  logits[g] = l;
  atomicMaxFloat(&lmax[d * NHEAD + h], l);
}

// -------- edge pass 2: exp + segment sum of denominators --------
__global__ __launch_bounds__(256) void edge_exp_kernel(
    const int* __restrict__ dst, float* __restrict__ logits,
    const float* __restrict__ lmax, float* __restrict__ den) {
  int g = blockIdx.x * blockDim.x + threadIdx.x;
  if (g >= N_EDGES * NHEAD) return;
  int e = g >> 2, h = g & 3;
  int d = dst[e];
  float ex = expf(logits[g] - lmax[d * NHEAD + h]);
  logits[g] = ex;  // in-place: logits buffer now holds ex
  unsafeAtomicAdd(&den[d * NHEAD + h], ex);
}

// -------- edge pass 3: weighted message scatter-add --------
#define EPB 16
__global__ __launch_bounds__(256) void edge_msg_kernel(
    const int* __restrict__ src, const int* __restrict__ dst,
    const float* __restrict__ ex, const float* __restrict__ xs,
    float* __restrict__ acc) {
  int t = threadIdx.x;      // t = h*64 + c
  int h = t >> 6;
  int e0 = blockIdx.x * EPB;
  int e1 = min(e0 + EPB, N_EDGES);
  for (int e = e0; e < e1; ++e) {
    int s = src[e], d = dst[e];
    float w = ex[(size_t)e * NHEAD + h];
    float v = w * xs[(size_t)s * HC + t];
    unsafeAtomicAdd(&acc[(size_t)d * HC + t], v);
  }
}

// -------- node epilogue: normalize, head-mean, bias, (relu) --------
__global__ __launch_bounds__(256) void node_finish_kernel(
    const float* __restrict__ acc, const float* __restrict__ den,
    const float* __restrict__ b, float* __restrict__ out, int relu) {
  int g = blockIdx.x * blockDim.x + threadIdx.x;
  if (g >= N_NODES * 64) return;
  int n = g >> 6, c = g & 63;
  float sum = 0.f;
#pragma unroll
  for (int h = 0; h < NHEAD; ++h) {
    float dn = den[n * NHEAD + h];
    float a = acc[(size_t)n * HC + h * 64 + c];
    sum += (dn > 0.f) ? (a / dn) : 0.f;
  }
  float v = sum * 0.25f + b[c];
  if (relu) v = fmaxf(v, 0.f);
  out[g] = v;
}

extern "C" void kernel_launch(void* const* d_in, const int* in_sizes, int n_in,
                              void* d_out, int out_size, void* d_ws, size_t ws_size,
                              hipStream_t stream) {
  const float* x   = (const float*)d_in[0];
  const int* eidx  = (const int*)d_in[1];
  const int* etype = (const int*)d_in[2];
  const float* rel1 = (const float*)d_in[3];
  const float* W1   = (const float*)d_in[4];
  const float* We1  = (const float*)d_in[5];
  const float* as1  = (const float*)d_in[6];
  const float* ad1  = (const float*)d_in[7];
  const float* ae1  = (const float*)d_in[8];
  const float* b1   = (const float*)d_in[9];
  const float* rel2 = (const float*)d_in[10];
  const float* W2   = (const float*)d_in[11];
  const float* We2  = (const float*)d_in[12];
  const float* as2  = (const float*)d_in[13];
  const float* ad2  = (const float*)d_in[14];
  const float* ae2  = (const float*)d_in[15];
  const float* b2   = (const float*)d_in[16];
  const int* src = eidx;
  const int* dst = eidx + N_EDGES;

  float* ws = (float*)d_ws;
  float* xs     = ws;                                  // N*256
  float* acc    = xs + (size_t)N_NODES * HC;           // N*256
  float* logits = acc + (size_t)N_NODES * HC;          // E*4
  float* lmax   = logits + (size_t)N_EDGES * NHEAD;    // N*4
  float* den    = lmax + (size_t)N_NODES * NHEAD;      // N*4
  float* asrc   = den + (size_t)N_NODES * NHEAD;       // N*4
  float* adst   = asrc + (size_t)N_NODES * NHEAD;      // N*4
  float* tab    = adst + (size_t)N_NODES * NHEAD;      // R*4
  float* h1     = tab + NREL * NHEAD;                  // N*64

  const int EH = N_EDGES * NHEAD;

  // ================= layer 1 =================
  gemm_xw<<<(N_NODES + 31) / 32, 256, 0, stream>>>(x, W1, xs, N_NODES, IN_DIM);
  alpha_kernel<<<(N_NODES * NHEAD * 64 + 255) / 256, 256, 0, stream>>>(xs, as1, ad1, asrc, adst);
  relalpha_kernel<<<NREL, 256, 0, stream>>>(rel1, We1, ae1, tab, IN_DIM);
  hipMemsetAsync(lmax, 0xFF, (size_t)N_NODES * NHEAD * sizeof(float), stream);
  hipMemsetAsync(den, 0, (size_t)N_NODES * NHEAD * sizeof(float), stream);
  hipMemsetAsync(acc, 0, (size_t)N_NODES * HC * sizeof(float), stream);
  edge_logits_kernel<<<(EH + 255) / 256, 256, 0, stream>>>(src, dst, etype, asrc, adst, tab, logits, lmax);
  edge_exp_kernel<<<(EH + 255) / 256, 256, 0, stream>>>(dst, logits, lmax, den);
  edge_msg_kernel<<<(N_EDGES + EPB - 1) / EPB, 256, 0, stream>>>(src, dst, logits, xs, acc);
  node_finish_kernel<<<(N_NODES * 64 + 255) / 256, 256, 0, stream>>>(acc, den, b1, h1, 1);

  // ================= layer 2 =================
  gemm_xw<<<(N_NODES + 31) / 32, 256, 0, stream>>>(h1, W2, xs, N_NODES, 64);
  alpha_kernel<<<(N_NODES * NHEAD * 64 + 255) / 256, 256, 0, stream>>>(xs, as2, ad2, asrc, adst);
  relalpha_kernel<<<NREL, 256, 0, stream>>>(rel2, We2, ae2, tab, 64);
  hipMemsetAsync(lmax, 0xFF, (size_t)N_NODES * NHEAD * sizeof(float), stream);
  hipMemsetAsync(den, 0, (size_t)N_NODES * NHEAD * sizeof(float), stream);
  hipMemsetAsync(acc, 0, (size_t)N_NODES * HC * sizeof(float), stream);
  edge_logits_kernel<<<(EH + 255) / 256, 256, 0, stream>>>(src, dst, etype, asrc, adst, tab, logits, lmax);
  edge_exp_kernel<<<(EH + 255) / 256, 256, 0, stream>>>(dst, logits, lmax, den);
  edge_msg_kernel<<<(N_EDGES + EPB - 1) / EPB, 256, 0, stream>>>(src, dst, logits, xs, acc);
  node_finish_kernel<<<(N_NODES * 64 + 255) / 256, 256, 0, stream>>>(acc, den, b2, (float*)d_out, 0);
}

// Round 3
// 680.702 us; speedup vs baseline: 2.5528x; 2.5528x over previous
//
#include <hip/hip_runtime.h>
#include <hip/hip_bf16.h>
#include <math.h>

#define N_NODES 50000
#define N_EDGES 800000
#define IN_DIM 128
#define NHEAD 4
#define NREL 64
#define HC 256              // NHEAD * 64 (both layers: H*HID = H*OUT = 256)
#define NEG_SLOPE 0.2f

// ============ GEMM: Y[M x 256] = X[M x K] @ W[K x 256] ============
__global__ __launch_bounds__(256) void gemm_xw(
    const float* __restrict__ X, const float* __restrict__ W,
    float* __restrict__ Y, int M, int K) {
  __shared__ __align__(16) float wlds[32][256];   // [kk][col]
  __shared__ __align__(16) float xlds[32][36];    // [kk][row], padded
  const int t = threadIdx.x;
  const int wv = t >> 6;          // wave id 0..3 -> rows wv*8..wv*8+7
  const int tx = t & 63;          // lane -> cols tx*4..tx*4+3
  const int c4 = tx * 4;
  const int rbase = wv * 8;
  const int row0 = blockIdx.x * 32;

  float acc[8][4];
#pragma unroll
  for (int r = 0; r < 8; ++r)
#pragma unroll
    for (int c = 0; c < 4; ++c) acc[r][c] = 0.f;

  for (int kb = 0; kb < K; kb += 32) {
    __syncthreads();
#pragma unroll
    for (int i = 0; i < 8; ++i) {
      int rr = i * 4 + wv;
      *(float4*)&wlds[rr][c4] = *(const float4*)&W[(size_t)(kb + rr) * HC + c4];
    }
    {
      int r = t >> 3;
      int kk = (t & 7) * 4;
      int row = row0 + r;
      float4 xv = make_float4(0.f, 0.f, 0.f, 0.f);
      if (row < M) xv = *(const float4*)&X[(size_t)row * K + kb + kk];
      xlds[kk + 0][r] = xv.x;
      xlds[kk + 1][r] = xv.y;
      xlds[kk + 2][r] = xv.z;
      xlds[kk + 3][r] = xv.w;
    }
    __syncthreads();
#pragma unroll
    for (int kk = 0; kk < 32; ++kk) {
      const float4 w4 = *(const float4*)&wlds[kk][c4];
      const float4 xa = *(const float4*)&xlds[kk][rbase];
      const float4 xb = *(const float4*)&xlds[kk][rbase + 4];
      const float xr[8] = {xa.x, xa.y, xa.z, xa.w, xb.x, xb.y, xb.z, xb.w};
#pragma unroll
      for (int r = 0; r < 8; ++r) {
        acc[r][0] += xr[r] * w4.x;
        acc[r][1] += xr[r] * w4.y;
        acc[r][2] += xr[r] * w4.z;
        acc[r][3] += xr[r] * w4.w;
      }
    }
  }
#pragma unroll
  for (int r = 0; r < 8; ++r) {
    int row = row0 + rbase + r;
    if (row < M) {
      float4 o = make_float4(acc[r][0], acc[r][1], acc[r][2], acc[r][3]);
      *(float4*)&Y[(size_t)row * HC + c4] = o;
    }
  }
}

// ============ per-(node,head) attention coefficients ============
__global__ __launch_bounds__(256) void alpha_kernel(
    const float* __restrict__ xs, const float* __restrict__ a_s,
    const float* __restrict__ a_d, float* __restrict__ asrc,
    float* __restrict__ adst) {
  int gw = (blockIdx.x * blockDim.x + threadIdx.x) >> 6;
  int lane = threadIdx.x & 63;
  if (gw >= N_NODES * NHEAD) return;
  int n = gw >> 2, h = gw & 3;
  float v = xs[(size_t)n * HC + h * 64 + lane];
  float s = v * a_s[h * 64 + lane];
  float d = v * a_d[h * 64 + lane];
#pragma unroll
  for (int off = 32; off > 0; off >>= 1) {
    s += __shfl_down(s, off);
    d += __shfl_down(d, off);
  }
  if (lane == 0) {
    asrc[gw] = s;
    adst[gw] = d;
  }
}

// ============ per-relation alpha_e table [R, H] ============
__global__ __launch_bounds__(256) void relalpha_kernel(
    const float* __restrict__ rel, const float* __restrict__ We,
    const float* __restrict__ a_e, float* __restrict__ tab, int K) {
  int r = blockIdx.x;
  int t = threadIdx.x;  // col in [0,256)
  float acc = 0.f;
  for (int k = 0; k < K; ++k) acc += rel[(size_t)r * K + k] * We[(size_t)k * HC + t];
  int h = t >> 6, lane = t & 63;
  float p = acc * a_e[t];
#pragma unroll
  for (int off = 32; off > 0; off >>= 1) p += __shfl_down(p, off);
  if (lane == 0) tab[r * NHEAD + h] = p;
}

// ============ CSR build ============
__global__ __launch_bounds__(256) void hist_kernel(
    const int* __restrict__ dst, int* __restrict__ deg) {
  int e = blockIdx.x * blockDim.x + threadIdx.x;
  if (e < N_EDGES) atomicAdd(&deg[dst[e]], 1);
}

// single-block exclusive scan of deg[0..N) -> rowptr, cursor
__global__ __launch_bounds__(256) void scan_kernel(
    const int* __restrict__ deg, int* __restrict__ rowptr,
    int* __restrict__ cursor) {
  __shared__ int sums[256];
  const int CH = (N_NODES + 255) / 256;   // 196
  int t = threadIdx.x;
  int base = t * CH;
  int local = 0;
  for (int i = 0; i < CH; ++i) {
    int idx = base + i;
    if (idx < N_NODES) local += deg[idx];
  }
  sums[t] = local;
  __syncthreads();
  // Hillis-Steele inclusive scan over 256 partials
  for (int off = 1; off < 256; off <<= 1) {
    int v = (t >= off) ? sums[t - off] : 0;
    __syncthreads();
    sums[t] += v;
    __syncthreads();
  }
  int run = (t == 0) ? 0 : sums[t - 1];
  for (int i = 0; i < CH; ++i) {
    int idx = base + i;
    if (idx < N_NODES) {
      rowptr[idx] = run;
      cursor[idx] = run;
      run += deg[idx];
    }
  }
  if (t == 0) rowptr[N_NODES] = N_EDGES;
}

__global__ __launch_bounds__(256) void fill_kernel(
    const int* __restrict__ src, const int* __restrict__ dst,
    const int* __restrict__ etype, int* __restrict__ cursor,
    int* __restrict__ csr_src, int* __restrict__ csr_et) {
  int e = blockIdx.x * blockDim.x + threadIdx.x;
  if (e >= N_EDGES) return;
  int d = dst[e];
  int i = atomicAdd(&cursor[d], 1);
  csr_src[i] = src[e];
  csr_et[i] = etype[e];
}

// ============ per-dst-node softmax over incoming edges (1 wave/node) ============
__global__ __launch_bounds__(256) void edge_softmax_kernel(
    const int* __restrict__ rowptr, const int* __restrict__ csr_src,
    const int* __restrict__ csr_et, const float* __restrict__ asrc,
    const float* __restrict__ adst, const float* __restrict__ tab,
    float* __restrict__ ex_p, float* __restrict__ rden) {
  int wv = (blockIdx.x * blockDim.x + threadIdx.x) >> 6;
  if (wv >= N_NODES) return;
  int n = wv;
  int lane = threadIdx.x & 63;
  int h = lane & 3, j0 = lane >> 2;       // 16 edge-slots x 4 heads
  int i0 = rowptr[n], i1 = rowptr[n + 1];
  float adn = adst[n * NHEAD + h];
  float m = -1e30f;
  for (int i = i0 + j0; i < i1; i += 16) {
    int s = csr_src[i], r = csr_et[i];
    float l = asrc[s * NHEAD + h] + adn + tab[r * NHEAD + h];
    l = (l >= 0.f) ? l : NEG_SLOPE * l;
    ex_p[(size_t)i * NHEAD + h] = l;      // raw logit for now
    m = fmaxf(m, l);
  }
#pragma unroll
  for (int off = 4; off < 64; off <<= 1) m = fmaxf(m, __shfl_xor(m, off));
  float sden = 0.f;
  for (int i = i0 + j0; i < i1; i += 16) {
    float ex = expf(ex_p[(size_t)i * NHEAD + h] - m);
    ex_p[(size_t)i * NHEAD + h] = ex;
    sden += ex;
  }
#pragma unroll
  for (int off = 4; off < 64; off <<= 1) sden += __shfl_xor(sden, off);
  // lanes 0..3 (j0==0) hold the full per-head sums; h == lane there.
  if (j0 == 0) rden[n * NHEAD + h] = (sden > 0.f) ? (1.0f / sden) : 0.f;
}

// ============ gather + weighted sum + normalize + head-mean + bias (+relu) ============
__global__ __launch_bounds__(256) void gather_msg_kernel(
    const int* __restrict__ rowptr, const int* __restrict__ csr_src,
    const float* __restrict__ ex_p, const float* __restrict__ xs,
    const float* __restrict__ rden, const float* __restrict__ b,
    float* __restrict__ out, int relu) {
  int n = blockIdx.x;
  int t = threadIdx.x;
  int wv = t >> 6, lane = t & 63;
  int i0 = rowptr[n], i1 = rowptr[n + 1];
  int hh = lane >> 4;                     // head of this lane's 4 floats
  float4 acc = make_float4(0.f, 0.f, 0.f, 0.f);
  for (int i = i0 + wv; i < i1; i += 4) {
    int s = csr_src[i];
    float w = ex_p[(size_t)i * NHEAD + hh];
    const float4 v = *(const float4*)&xs[(size_t)s * HC + lane * 4];
    acc.x += w * v.x; acc.y += w * v.y; acc.z += w * v.z; acc.w += w * v.w;
  }
  __shared__ __align__(16) float lds[4 * 256];
  *(float4*)&lds[t * 4] = acc;            // [wv][lane*4..]
  __syncthreads();
  if (t < 64) {
    int c = t;
    float sum = 0.f;
#pragma unroll
    for (int h = 0; h < NHEAD; ++h) {
      int p = h * 64 + c;
      float a = lds[p] + lds[256 + p] + lds[512 + p] + lds[768 + p];
      sum += a * rden[n * NHEAD + h];
    }
    float v = sum * 0.25f + b[c];
    if (relu) v = fmaxf(v, 0.f);
    out[(size_t)n * 64 + c] = v;
  }
}

extern "C" void kernel_launch(void* const* d_in, const int* in_sizes, int n_in,
                              void* d_out, int out_size, void* d_ws, size_t ws_size,
                              hipStream_t stream) {
  const float* x   = (const float*)d_in[0];
  const int* eidx  = (const int*)d_in[1];
  const int* etype = (const int*)d_in[2];
  const float* rel1 = (const float*)d_in[3];
  const float* W1   = (const float*)d_in[4];
  const float* We1  = (const float*)d_in[5];
  const float* as1  = (const float*)d_in[6];
  const float* ad1  = (const float*)d_in[7];
  const float* ae1  = (const float*)d_in[8];
  const float* b1   = (const float*)d_in[9];
  const float* rel2 = (const float*)d_in[10];
  const float* W2   = (const float*)d_in[11];
  const float* We2  = (const float*)d_in[12];
  const float* as2  = (const float*)d_in[13];
  const float* ad2  = (const float*)d_in[14];
  const float* ae2  = (const float*)d_in[15];
  const float* b2   = (const float*)d_in[16];
  const int* src = eidx;
  const int* dst = eidx + N_EDGES;

  // ---- workspace layout ----
  float* ws = (float*)d_ws;
  float* xs   = ws;                                   // N*256
  float* ex_p = xs + (size_t)N_NODES * HC;            // E*4
  float* asrc = ex_p + (size_t)N_EDGES * NHEAD;       // N*4
  float* adst = asrc + (size_t)N_NODES * NHEAD;       // N*4
  float* rden = adst + (size_t)N_NODES * NHEAD;       // N*4
  float* tab  = rden + (size_t)N_NODES * NHEAD;       // R*4
  float* h1   = tab + NREL * NHEAD;                   // N*64
  int* ip = (int*)(h1 + (size_t)N_NODES * 64);
  int* deg     = ip;                                  // N
  int* rowptr  = deg + N_NODES;                       // N+1
  int* cursor  = rowptr + N_NODES + 1;                // N
  int* csr_src = cursor + N_NODES;                    // E
  int* csr_et  = csr_src + N_EDGES;                   // E

  // ---- CSR build (graph is shared by both layers) ----
  hipMemsetAsync(deg, 0, N_NODES * sizeof(int), stream);
  hist_kernel<<<(N_EDGES + 255) / 256, 256, 0, stream>>>(dst, deg);
  scan_kernel<<<1, 256, 0, stream>>>(deg, rowptr, cursor);
  fill_kernel<<<(N_EDGES + 255) / 256, 256, 0, stream>>>(src, dst, etype, cursor, csr_src, csr_et);

  const int NW = (N_NODES * 64 + 255) / 256;   // blocks for 1-wave-per-node kernels

  // ================= layer 1 =================
  gemm_xw<<<(N_NODES + 31) / 32, 256, 0, stream>>>(x, W1, xs, N_NODES, IN_DIM);
  alpha_kernel<<<(N_NODES * NHEAD * 64 + 255) / 256, 256, 0, stream>>>(xs, as1, ad1, asrc, adst);
  relalpha_kernel<<<NREL, 256, 0, stream>>>(rel1, We1, ae1, tab, IN_DIM);
  edge_softmax_kernel<<<NW, 256, 0, stream>>>(rowptr, csr_src, csr_et, asrc, adst, tab, ex_p, rden);
  gather_msg_kernel<<<N_NODES, 256, 0, stream>>>(rowptr, csr_src, ex_p, xs, rden, b1, h1, 1);

  // ================= layer 2 =================
  gemm_xw<<<(N_NODES + 31) / 32, 256, 0, stream>>>(h1, W2, xs, N_NODES, 64);
  alpha_kernel<<<(N_NODES * NHEAD * 64 + 255) / 256, 256, 0, stream>>>(xs, as2, ad2, asrc, adst);
  relalpha_kernel<<<NREL, 256, 0, stream>>>(rel2, We2, ae2, tab, 64);
  edge_softmax_kernel<<<NW, 256, 0, stream>>>(rowptr, csr_src, csr_et, asrc, adst, tab, ex_p, rden);
  gather_msg_kernel<<<N_NODES, 256, 0, stream>>>(rowptr, csr_src, ex_p, xs, rden, b2, (float*)d_out, 0);
}

// Round 4
// 510.727 us; speedup vs baseline: 3.4024x; 1.3328x over previous
//
#include <hip/hip_runtime.h>
#include <hip/hip_bf16.h>
#include <math.h>

#define N_NODES 50000
#define N_EDGES 800000
#define IN_DIM 128
#define NHEAD 4
#define NREL 64
#define HC 256              // NHEAD * 64 (both layers: H*HID = H*OUT = 256)
#define NEG_SLOPE 0.2f
#define SCAN_B ((N_NODES + 255) / 256)   // 196 blocks

// ============ GEMM + fused alpha: Y = X@W, asrc/adst = per-head dots ============
__global__ __launch_bounds__(256) void gemm_xw_alpha(
    const float* __restrict__ X, const float* __restrict__ W,
    const float* __restrict__ a_s, const float* __restrict__ a_d,
    float* __restrict__ Y, float* __restrict__ asrc, float* __restrict__ adst,
    int M, int K) {
  __shared__ __align__(16) float wlds[32][256];   // [kk][col]
  __shared__ __align__(16) float xlds[32][36];    // [kk][row], padded
  const int t = threadIdx.x;
  const int wv = t >> 6;          // wave id 0..3 -> rows wv*8..wv*8+7
  const int tx = t & 63;          // lane -> cols tx*4..tx*4+3
  const int c4 = tx * 4;
  const int rbase = wv * 8;
  const int row0 = blockIdx.x * 32;

  float acc[8][4];
#pragma unroll
  for (int r = 0; r < 8; ++r)
#pragma unroll
    for (int c = 0; c < 4; ++c) acc[r][c] = 0.f;

  for (int kb = 0; kb < K; kb += 32) {
    __syncthreads();
#pragma unroll
    for (int i = 0; i < 8; ++i) {
      int rr = i * 4 + wv;
      *(float4*)&wlds[rr][c4] = *(const float4*)&W[(size_t)(kb + rr) * HC + c4];
    }
    {
      int r = t >> 3;
      int kk = (t & 7) * 4;
      int row = row0 + r;
      float4 xv = make_float4(0.f, 0.f, 0.f, 0.f);
      if (row < M) xv = *(const float4*)&X[(size_t)row * K + kb + kk];
      xlds[kk + 0][r] = xv.x;
      xlds[kk + 1][r] = xv.y;
      xlds[kk + 2][r] = xv.z;
      xlds[kk + 3][r] = xv.w;
    }
    __syncthreads();
#pragma unroll
    for (int kk = 0; kk < 32; ++kk) {
      const float4 w4 = *(const float4*)&wlds[kk][c4];
      const float4 xa = *(const float4*)&xlds[kk][rbase];
      const float4 xb = *(const float4*)&xlds[kk][rbase + 4];
      const float xr[8] = {xa.x, xa.y, xa.z, xa.w, xb.x, xb.y, xb.z, xb.w};
#pragma unroll
      for (int r = 0; r < 8; ++r) {
        acc[r][0] += xr[r] * w4.x;
        acc[r][1] += xr[r] * w4.y;
        acc[r][2] += xr[r] * w4.z;
        acc[r][3] += xr[r] * w4.w;
      }
    }
  }

  const float4 as4 = *(const float4*)&a_s[c4];
  const float4 ad4 = *(const float4*)&a_d[c4];
  const int h = tx >> 4;          // head owning cols c4..c4+3
#pragma unroll
  for (int r = 0; r < 8; ++r) {
    int row = row0 + rbase + r;
    if (row < M) {
      float4 o = make_float4(acc[r][0], acc[r][1], acc[r][2], acc[r][3]);
      *(float4*)&Y[(size_t)row * HC + c4] = o;
    }
    float sp = acc[r][0] * as4.x + acc[r][1] * as4.y + acc[r][2] * as4.z + acc[r][3] * as4.w;
    float dp = acc[r][0] * ad4.x + acc[r][1] * ad4.y + acc[r][2] * ad4.z + acc[r][3] * ad4.w;
#pragma unroll
    for (int off = 1; off < 16; off <<= 1) {
      sp += __shfl_xor(sp, off);
      dp += __shfl_xor(dp, off);
    }
    if ((tx & 15) == 0 && row < M) {
      asrc[row * NHEAD + h] = sp;
      adst[row * NHEAD + h] = dp;
    }
  }
}

// ============ per-relation alpha_e table [R, H] ============
__global__ __launch_bounds__(256) void relalpha_kernel(
    const float* __restrict__ rel, const float* __restrict__ We,
    const float* __restrict__ a_e, float* __restrict__ tab, int K) {
  int r = blockIdx.x;
  int t = threadIdx.x;  // col in [0,256)
  float acc = 0.f;
  for (int k = 0; k < K; ++k) acc += rel[(size_t)r * K + k] * We[(size_t)k * HC + t];
  int h = t >> 6, lane = t & 63;
  float p = acc * a_e[t];
#pragma unroll
  for (int off = 32; off > 0; off >>= 1) p += __shfl_down(p, off);
  if (lane == 0) tab[r * NHEAD + h] = p;
}

// ============ CSR build ============
__global__ __launch_bounds__(256) void hist_kernel(
    const int* __restrict__ dst, int* __restrict__ deg) {
  int e = blockIdx.x * blockDim.x + threadIdx.x;
  if (e < N_EDGES) atomicAdd(&deg[dst[e]], 1);
}

// per-block sums of deg
__global__ __launch_bounds__(256) void block_sum_kernel(
    const int* __restrict__ deg, int* __restrict__ bsum) {
  int i = blockIdx.x * 256 + threadIdx.x;
  int v = (i < N_NODES) ? deg[i] : 0;
#pragma unroll
  for (int off = 32; off > 0; off >>= 1) v += __shfl_down(v, off);
  __shared__ int w[4];
  if ((threadIdx.x & 63) == 0) w[threadIdx.x >> 6] = v;
  __syncthreads();
  if (threadIdx.x == 0) bsum[blockIdx.x] = w[0] + w[1] + w[2] + w[3];
}

// single-block exclusive scan of the 196 block sums
__global__ __launch_bounds__(256) void scan_bsum_kernel(
    const int* __restrict__ bsum, int* __restrict__ boff) {
  __shared__ int s[256];
  int t = threadIdx.x;
  int v = (t < SCAN_B) ? bsum[t] : 0;
  s[t] = v;
  __syncthreads();
  for (int off = 1; off < 256; off <<= 1) {
    int u = (t >= off) ? s[t - off] : 0;
    __syncthreads();
    s[t] += u;
    __syncthreads();
  }
  boff[t] = (t == 0) ? 0 : s[t - 1];
}

// per-block local scan + block offset -> rowptr, cursor
__global__ __launch_bounds__(256) void scan_final_kernel(
    const int* __restrict__ deg, const int* __restrict__ boff,
    int* __restrict__ rowptr, int* __restrict__ cursor) {
  __shared__ int s[256];
  int t = threadIdx.x;
  int i = blockIdx.x * 256 + t;
  int v = (i < N_NODES) ? deg[i] : 0;
  s[t] = v;
  __syncthreads();
  for (int off = 1; off < 256; off <<= 1) {
    int u = (t >= off) ? s[t - off] : 0;
    __syncthreads();
    s[t] += u;
    __syncthreads();
  }
  int excl = boff[blockIdx.x] + s[t] - v;   // inclusive - self = exclusive
  if (i < N_NODES) {
    rowptr[i] = excl;
    cursor[i] = excl;
  }
  if (t == 0 && blockIdx.x == 0) rowptr[N_NODES] = N_EDGES;
}

__global__ __launch_bounds__(256) void fill_kernel(
    const int* __restrict__ src, const int* __restrict__ dst,
    const int* __restrict__ etype, int* __restrict__ cursor,
    int* __restrict__ csr_src, int* __restrict__ csr_et) {
  int e = blockIdx.x * blockDim.x + threadIdx.x;
  if (e >= N_EDGES) return;
  int d = dst[e];
  int i = atomicAdd(&cursor[d], 1);
  csr_src[i] = src[e];
  csr_et[i] = etype[e];
}

// ============ per-dst-node softmax over incoming edges (1 wave/node) ============
__global__ __launch_bounds__(256) void edge_softmax_kernel(
    const int* __restrict__ rowptr, const int* __restrict__ csr_src,
    const int* __restrict__ csr_et, const float* __restrict__ asrc,
    const float* __restrict__ adst, const float* __restrict__ tab,
    float* __restrict__ ex_p, float* __restrict__ rden) {
  int wv = (blockIdx.x * blockDim.x + threadIdx.x) >> 6;
  if (wv >= N_NODES) return;
  int n = wv;
  int lane = threadIdx.x & 63;
  int h = lane & 3, j0 = lane >> 2;       // 16 edge-slots x 4 heads
  int i0 = rowptr[n], i1 = rowptr[n + 1];
  float adn = adst[n * NHEAD + h];
  float m = -1e30f;
  for (int i = i0 + j0; i < i1; i += 16) {
    int s = csr_src[i], r = csr_et[i];
    float l = asrc[s * NHEAD + h] + adn + tab[r * NHEAD + h];
    l = (l >= 0.f) ? l : NEG_SLOPE * l;
    ex_p[(size_t)i * NHEAD + h] = l;      // raw logit for now
    m = fmaxf(m, l);
  }
#pragma unroll
  for (int off = 4; off < 64; off <<= 1) m = fmaxf(m, __shfl_xor(m, off));
  float sden = 0.f;
  for (int i = i0 + j0; i < i1; i += 16) {
    float ex = expf(ex_p[(size_t)i * NHEAD + h] - m);
    ex_p[(size_t)i * NHEAD + h] = ex;
    sden += ex;
  }
#pragma unroll
  for (int off = 4; off < 64; off <<= 1) sden += __shfl_xor(sden, off);
  // lanes 0..3 (j0==0) hold the full per-head sums; h == lane there.
  if (j0 == 0) rden[n * NHEAD + h] = (sden > 0.f) ? (1.0f / sden) : 0.f;
}

// ============ gather + weighted sum + normalize + head-mean + bias (+relu) ============
__global__ __launch_bounds__(256) void gather_msg_kernel(
    const int* __restrict__ rowptr, const int* __restrict__ csr_src,
    const float* __restrict__ ex_p, const float* __restrict__ xs,
    const float* __restrict__ rden, const float* __restrict__ b,
    float* __restrict__ out, int relu) {
  int n = blockIdx.x;
  int t = threadIdx.x;
  int wv = t >> 6, lane = t & 63;
  int i0 = rowptr[n], i1 = rowptr[n + 1];
  int hh = lane >> 4;                     // head of this lane's 4 floats
  float4 acc = make_float4(0.f, 0.f, 0.f, 0.f);
  for (int i = i0 + wv; i < i1; i += 4) {
    int s = csr_src[i];
    float w = ex_p[(size_t)i * NHEAD + hh];
    const float4 v = *(const float4*)&xs[(size_t)s * HC + lane * 4];
    acc.x += w * v.x; acc.y += w * v.y; acc.z += w * v.z; acc.w += w * v.w;
  }
  __shared__ __align__(16) float lds[4 * 256];
  *(float4*)&lds[t * 4] = acc;            // [wv][lane*4..]
  __syncthreads();
  if (t < 64) {
    int c = t;
    float sum = 0.f;
#pragma unroll
    for (int h = 0; h < NHEAD; ++h) {
      int p = h * 64 + c;
      float a = lds[p] + lds[256 + p] + lds[512 + p] + lds[768 + p];
      sum += a * rden[n * NHEAD + h];
    }
    float v = sum * 0.25f + b[c];
    if (relu) v = fmaxf(v, 0.f);
    out[(size_t)n * 64 + c] = v;
  }
}

extern "C" void kernel_launch(void* const* d_in, const int* in_sizes, int n_in,
                              void* d_out, int out_size, void* d_ws, size_t ws_size,
                              hipStream_t stream) {
  const float* x   = (const float*)d_in[0];
  const int* eidx  = (const int*)d_in[1];
  const int* etype = (const int*)d_in[2];
  const float* rel1 = (const float*)d_in[3];
  const float* W1   = (const float*)d_in[4];
  const float* We1  = (const float*)d_in[5];
  const float* as1  = (const float*)d_in[6];
  const float* ad1  = (const float*)d_in[7];
  const float* ae1  = (const float*)d_in[8];
  const float* b1   = (const float*)d_in[9];
  const float* rel2 = (const float*)d_in[10];
  const float* W2   = (const float*)d_in[11];
  const float* We2  = (const float*)d_in[12];
  const float* as2  = (const float*)d_in[13];
  const float* ad2  = (const float*)d_in[14];
  const float* ae2  = (const float*)d_in[15];
  const float* b2   = (const float*)d_in[16];
  const int* src = eidx;
  const int* dst = eidx + N_EDGES;

  // ---- workspace layout ----
  float* ws = (float*)d_ws;
  float* xs   = ws;                                   // N*256
  float* ex_p = xs + (size_t)N_NODES * HC;            // E*4
  float* asrc = ex_p + (size_t)N_EDGES * NHEAD;       // N*4
  float* adst = asrc + (size_t)N_NODES * NHEAD;       // N*4
  float* rden = adst + (size_t)N_NODES * NHEAD;       // N*4
  float* tab  = rden + (size_t)N_NODES * NHEAD;       // R*4
  float* h1   = tab + NREL * NHEAD;                   // N*64
  int* ip = (int*)(h1 + (size_t)N_NODES * 64);
  int* deg     = ip;                                  // N
  int* rowptr  = deg + N_NODES;                       // N+1
  int* cursor  = rowptr + N_NODES + 1;                // N
  int* csr_src = cursor + N_NODES;                    // E
  int* csr_et  = csr_src + N_EDGES;                   // E
  int* bsum    = csr_et + N_EDGES;                    // 256
  int* boff    = bsum + 256;                          // 256

  // ---- CSR build (graph is shared by both layers) ----
  hipMemsetAsync(deg, 0, N_NODES * sizeof(int), stream);
  hist_kernel<<<(N_EDGES + 255) / 256, 256, 0, stream>>>(dst, deg);
  block_sum_kernel<<<SCAN_B, 256, 0, stream>>>(deg, bsum);
  scan_bsum_kernel<<<1, 256, 0, stream>>>(bsum, boff);
  scan_final_kernel<<<SCAN_B, 256, 0, stream>>>(deg, boff, rowptr, cursor);
  fill_kernel<<<(N_EDGES + 255) / 256, 256, 0, stream>>>(src, dst, etype, cursor, csr_src, csr_et);

  const int NW = (N_NODES * 64 + 255) / 256;   // blocks for 1-wave-per-node kernels

  // ================= layer 1 =================
  gemm_xw_alpha<<<(N_NODES + 31) / 32, 256, 0, stream>>>(x, W1, as1, ad1, xs, asrc, adst, N_NODES, IN_DIM);
  relalpha_kernel<<<NREL, 256, 0, stream>>>(rel1, We1, ae1, tab, IN_DIM);
  edge_softmax_kernel<<<NW, 256, 0, stream>>>(rowptr, csr_src, csr_et, asrc, adst, tab, ex_p, rden);
  gather_msg_kernel<<<N_NODES, 256, 0, stream>>>(rowptr, csr_src, ex_p, xs, rden, b1, h1, 1);

  // ================= layer 2 =================
  gemm_xw_alpha<<<(N_NODES + 31) / 32, 256, 0, stream>>>(h1, W2, as2, ad2, xs, asrc, adst, N_NODES, 64);
  relalpha_kernel<<<NREL, 256, 0, stream>>>(rel2, We2, ae2, tab, 64);
  edge_softmax_kernel<<<NW, 256, 0, stream>>>(rowptr, csr_src, csr_et, asrc, adst, tab, ex_p, rden);
  gather_msg_kernel<<<N_NODES, 256, 0, stream>>>(rowptr, csr_src, ex_p, xs, rden, b2, (float*)d_out, 0);
}

// Round 5
// 471.381 us; speedup vs baseline: 3.6864x; 1.0835x over previous
//
#include <hip/hip_runtime.h>
#include <hip/hip_bf16.h>
#include <math.h>

#define N_NODES 50000
#define N_EDGES 800000
#define IN_DIM 128
#define NHEAD 4
#define NREL 64
#define HC 256              // NHEAD * 64 (both layers: H*HID = H*OUT = 256)
#define NEG_SLOPE 0.2f
#define SCAN_B ((N_NODES + 255) / 256)   // 196 blocks
#define CHUNK 64            // edges per online-softmax chunk

// ============ GEMM + fused alpha: Y = X@W, asrc/adst = per-head dots ============
__global__ __launch_bounds__(256) void gemm_xw_alpha(
    const float* __restrict__ X, const float* __restrict__ W,
    const float* __restrict__ a_s, const float* __restrict__ a_d,
    float* __restrict__ Y, float* __restrict__ asrc, float* __restrict__ adst,
    int M, int K) {
  __shared__ __align__(16) float wlds[32][256];   // [kk][col]
  __shared__ __align__(16) float xlds[32][36];    // [kk][row], padded
  const int t = threadIdx.x;
  const int wv = t >> 6;          // wave id 0..3 -> rows wv*8..wv*8+7
  const int tx = t & 63;          // lane -> cols tx*4..tx*4+3
  const int c4 = tx * 4;
  const int rbase = wv * 8;
  const int row0 = blockIdx.x * 32;

  float acc[8][4];
#pragma unroll
  for (int r = 0; r < 8; ++r)
#pragma unroll
    for (int c = 0; c < 4; ++c) acc[r][c] = 0.f;

  for (int kb = 0; kb < K; kb += 32) {
    __syncthreads();
#pragma unroll
    for (int i = 0; i < 8; ++i) {
      int rr = i * 4 + wv;
      *(float4*)&wlds[rr][c4] = *(const float4*)&W[(size_t)(kb + rr) * HC + c4];
    }
    {
      int r = t >> 3;
      int kk = (t & 7) * 4;
      int row = row0 + r;
      float4 xv = make_float4(0.f, 0.f, 0.f, 0.f);
      if (row < M) xv = *(const float4*)&X[(size_t)row * K + kb + kk];
      xlds[kk + 0][r] = xv.x;
      xlds[kk + 1][r] = xv.y;
      xlds[kk + 2][r] = xv.z;
      xlds[kk + 3][r] = xv.w;
    }
    __syncthreads();
#pragma unroll
    for (int kk = 0; kk < 32; ++kk) {
      const float4 w4 = *(const float4*)&wlds[kk][c4];
      const float4 xa = *(const float4*)&xlds[kk][rbase];
      const float4 xb = *(const float4*)&xlds[kk][rbase + 4];
      const float xr[8] = {xa.x, xa.y, xa.z, xa.w, xb.x, xb.y, xb.z, xb.w};
#pragma unroll
      for (int r = 0; r < 8; ++r) {
        acc[r][0] += xr[r] * w4.x;
        acc[r][1] += xr[r] * w4.y;
        acc[r][2] += xr[r] * w4.z;
        acc[r][3] += xr[r] * w4.w;
      }
    }
  }

  const float4 as4 = *(const float4*)&a_s[c4];
  const float4 ad4 = *(const float4*)&a_d[c4];
  const int h = tx >> 4;          // head owning cols c4..c4+3
#pragma unroll
  for (int r = 0; r < 8; ++r) {
    int row = row0 + rbase + r;
    if (row < M) {
      float4 o = make_float4(acc[r][0], acc[r][1], acc[r][2], acc[r][3]);
      *(float4*)&Y[(size_t)row * HC + c4] = o;
    }
    float sp = acc[r][0] * as4.x + acc[r][1] * as4.y + acc[r][2] * as4.z + acc[r][3] * as4.w;
    float dp = acc[r][0] * ad4.x + acc[r][1] * ad4.y + acc[r][2] * ad4.z + acc[r][3] * ad4.w;
#pragma unroll
    for (int off = 1; off < 16; off <<= 1) {
      sp += __shfl_xor(sp, off);
      dp += __shfl_xor(dp, off);
    }
    if ((tx & 15) == 0 && row < M) {
      asrc[row * NHEAD + h] = sp;
      adst[row * NHEAD + h] = dp;
    }
  }
}

// ============ per-relation alpha_e table [R, H] ============
__global__ __launch_bounds__(256) void relalpha_kernel(
    const float* __restrict__ rel, const float* __restrict__ We,
    const float* __restrict__ a_e, float* __restrict__ tab, int K) {
  int r = blockIdx.x;
  int t = threadIdx.x;  // col in [0,256)
  float acc = 0.f;
  for (int k = 0; k < K; ++k) acc += rel[(size_t)r * K + k] * We[(size_t)k * HC + t];
  int h = t >> 6, lane = t & 63;
  float p = acc * a_e[t];
#pragma unroll
  for (int off = 32; off > 0; off >>= 1) p += __shfl_down(p, off);
  if (lane == 0) tab[r * NHEAD + h] = p;
}

// ============ CSR build ============
__global__ __launch_bounds__(256) void hist_kernel(
    const int* __restrict__ dst, int* __restrict__ deg) {
  int e = blockIdx.x * blockDim.x + threadIdx.x;
  if (e < N_EDGES) atomicAdd(&deg[dst[e]], 1);
}

__global__ __launch_bounds__(256) void block_sum_kernel(
    const int* __restrict__ deg, int* __restrict__ bsum) {
  int i = blockIdx.x * 256 + threadIdx.x;
  int v = (i < N_NODES) ? deg[i] : 0;
#pragma unroll
  for (int off = 32; off > 0; off >>= 1) v += __shfl_down(v, off);
  __shared__ int w[4];
  if ((threadIdx.x & 63) == 0) w[threadIdx.x >> 6] = v;
  __syncthreads();
  if (threadIdx.x == 0) bsum[blockIdx.x] = w[0] + w[1] + w[2] + w[3];
}

__global__ __launch_bounds__(256) void scan_bsum_kernel(
    const int* __restrict__ bsum, int* __restrict__ boff) {
  __shared__ int s[256];
  int t = threadIdx.x;
  int v = (t < SCAN_B) ? bsum[t] : 0;
  s[t] = v;
  __syncthreads();
  for (int off = 1; off < 256; off <<= 1) {
    int u = (t >= off) ? s[t - off] : 0;
    __syncthreads();
    s[t] += u;
    __syncthreads();
  }
  boff[t] = (t == 0) ? 0 : s[t - 1];
}

__global__ __launch_bounds__(256) void scan_final_kernel(
    const int* __restrict__ deg, const int* __restrict__ boff,
    int* __restrict__ rowptr, int* __restrict__ cursor) {
  __shared__ int s[256];
  int t = threadIdx.x;
  int i = blockIdx.x * 256 + t;
  int v = (i < N_NODES) ? deg[i] : 0;
  s[t] = v;
  __syncthreads();
  for (int off = 1; off < 256; off <<= 1) {
    int u = (t >= off) ? s[t - off] : 0;
    __syncthreads();
    s[t] += u;
    __syncthreads();
  }
  int excl = boff[blockIdx.x] + s[t] - v;
  if (i < N_NODES) {
    rowptr[i] = excl;
    cursor[i] = excl;
  }
  if (t == 0 && blockIdx.x == 0) rowptr[N_NODES] = N_EDGES;
}

__global__ __launch_bounds__(256) void fill_kernel(
    const int* __restrict__ src, const int* __restrict__ dst,
    const int* __restrict__ etype, int* __restrict__ cursor,
    int* __restrict__ csr_src, int* __restrict__ csr_et) {
  int e = blockIdx.x * blockDim.x + threadIdx.x;
  if (e >= N_EDGES) return;
  int d = dst[e];
  int i = atomicAdd(&cursor[d], 1);
  csr_src[i] = src[e];
  csr_et[i] = etype[e];
}

// ============ fused online-softmax + gather, 1 block per dst node ============
__global__ __launch_bounds__(256) void gat_node_kernel(
    const int* __restrict__ rowptr, const int* __restrict__ csr_src,
    const int* __restrict__ csr_et, const float* __restrict__ asrc,
    const float* __restrict__ adst, const float* __restrict__ tab,
    const float* __restrict__ xs, const float* __restrict__ b,
    float* __restrict__ out, int relu) {
  const int n = blockIdx.x;
  const int t = threadIdx.x;
  const int wv = t >> 6, lane = t & 63;
  const int eh = t >> 2, h = t & 3;       // phase-A role: edge slot x head
  const int hh = lane >> 4;               // phase-B role: head of this lane's cols
  const int i0 = rowptr[n], i1 = rowptr[n + 1];

  __shared__ float lds_p[CHUNK * NHEAD];  // exp(l - m) per (edge,head)
  __shared__ int   lds_idx[CHUNK];
  __shared__ float lds_r[16];             // per-wave per-head partials
  __shared__ float sm[NHEAD], sf[NHEAD], sden[NHEAD];
  __shared__ __align__(16) float lds4[1024];

  if (t < NHEAD) { sm[t] = -1e30f; sden[t] = 0.f; }
  float4 acc = make_float4(0.f, 0.f, 0.f, 0.f);
  const float adn = adst[n * NHEAD + h];
  __syncthreads();

  for (int ib = i0; ib < i1; ib += CHUNK) {
    const int nE = min(CHUNK, i1 - ib);
    // ---- Phase A: logits for nE edges x 4 heads ----
    float l = -1e30f;
    if (eh < nE) {
      int s = csr_src[ib + eh];
      int r = csr_et[ib + eh];
      l = asrc[s * NHEAD + h] + adn + tab[r * NHEAD + h];
      l = (l >= 0.f) ? l : NEG_SLOPE * l;
      if (h == 0) lds_idx[eh] = s;
    }
    // wave-level per-head max (xor offs multiple of 4 keep h invariant)
    float mx = l;
#pragma unroll
    for (int off = 4; off < 64; off <<= 1) mx = fmaxf(mx, __shfl_xor(mx, off));
    if (lane < 4) lds_r[wv * 4 + lane] = mx;
    __syncthreads();
    if (t < NHEAD) {
      float mn = fmaxf(fmaxf(lds_r[t], lds_r[4 + t]), fmaxf(lds_r[8 + t], lds_r[12 + t]));
      mn = fmaxf(mn, sm[t]);
      sf[t] = expf(sm[t] - mn);
      sm[t] = mn;
    }
    __syncthreads();
    float p = (eh < nE) ? expf(l - sm[h]) : 0.f;
    lds_p[t] = p;
    float sp = p;
#pragma unroll
    for (int off = 4; off < 64; off <<= 1) sp += __shfl_xor(sp, off);
    if (lane < 4) lds_r[wv * 4 + lane] = sp;
    __syncthreads();
    if (t < NHEAD)
      sden[t] = sden[t] * sf[t] + (lds_r[t] + lds_r[4 + t] + lds_r[8 + t] + lds_r[12 + t]);
    // rescale running accumulator by this head's factor
    {
      const float f = sf[hh];
      acc.x *= f; acc.y *= f; acc.z *= f; acc.w *= f;
    }
    // ---- Phase B: gather rows with 4 loads in flight ----
    const int cbase = lane << 2;
    for (int j = wv; j < nE; j += 16) {
      int j1 = j + 4, j2 = j + 8, j3 = j + 12;
      int s0 = lds_idx[j];                   float w0 = lds_p[j * 4 + hh];
      int s1 = (j1 < nE) ? lds_idx[j1] : s0; float w1 = (j1 < nE) ? lds_p[j1 * 4 + hh] : 0.f;
      int s2 = (j2 < nE) ? lds_idx[j2] : s0; float w2 = (j2 < nE) ? lds_p[j2 * 4 + hh] : 0.f;
      int s3 = (j3 < nE) ? lds_idx[j3] : s0; float w3 = (j3 < nE) ? lds_p[j3 * 4 + hh] : 0.f;
      const float4 v0 = *(const float4*)&xs[(size_t)s0 * HC + cbase];
      const float4 v1 = *(const float4*)&xs[(size_t)s1 * HC + cbase];
      const float4 v2 = *(const float4*)&xs[(size_t)s2 * HC + cbase];
      const float4 v3 = *(const float4*)&xs[(size_t)s3 * HC + cbase];
      acc.x += w0 * v0.x + w1 * v1.x + w2 * v2.x + w3 * v3.x;
      acc.y += w0 * v0.y + w1 * v1.y + w2 * v2.y + w3 * v3.y;
      acc.z += w0 * v0.z + w1 * v1.z + w2 * v2.z + w3 * v3.z;
      acc.w += w0 * v0.w + w1 * v1.w + w2 * v2.w + w3 * v3.w;
    }
    __syncthreads();   // protect lds_* for next chunk; also publishes sden
  }

  // ---- epilogue: cross-wave reduce, normalize, head-mean, bias ----
  *(float4*)&lds4[t * 4] = acc;
  __syncthreads();
  if (t < 64) {
    const int c = t;
    float sum = 0.f;
#pragma unroll
    for (int h2 = 0; h2 < NHEAD; ++h2) {
      int p = h2 * 64 + c;
      float a = lds4[p] + lds4[256 + p] + lds4[512 + p] + lds4[768 + p];
      float rd = (sden[h2] > 0.f) ? (1.0f / sden[h2]) : 0.f;
      sum += a * rd;
    }
    float v = sum * 0.25f + b[c];
    if (relu) v = fmaxf(v, 0.f);
    out[(size_t)n * 64 + c] = v;
  }
}

extern "C" void kernel_launch(void* const* d_in, const int* in_sizes, int n_in,
                              void* d_out, int out_size, void* d_ws, size_t ws_size,
                              hipStream_t stream) {
  const float* x   = (const float*)d_in[0];
  const int* eidx  = (const int*)d_in[1];
  const int* etype = (const int*)d_in[2];
  const float* rel1 = (const float*)d_in[3];
  const float* W1   = (const float*)d_in[4];
  const float* We1  = (const float*)d_in[5];
  const float* as1  = (const float*)d_in[6];
  const float* ad1  = (const float*)d_in[7];
  const float* ae1  = (const float*)d_in[8];
  const float* b1   = (const float*)d_in[9];
  const float* rel2 = (const float*)d_in[10];
  const float* W2   = (const float*)d_in[11];
  const float* We2  = (const float*)d_in[12];
  const float* as2  = (const float*)d_in[13];
  const float* ad2  = (const float*)d_in[14];
  const float* ae2  = (const float*)d_in[15];
  const float* b2   = (const float*)d_in[16];
  const int* src = eidx;
  const int* dst = eidx + N_EDGES;

  // ---- workspace layout ----
  float* ws = (float*)d_ws;
  float* xs   = ws;                                   // N*256
  float* asrc = xs + (size_t)N_NODES * HC;            // N*4
  float* adst = asrc + (size_t)N_NODES * NHEAD;       // N*4
  float* tab  = adst + (size_t)N_NODES * NHEAD;       // R*4
  float* h1   = tab + NREL * NHEAD;                   // N*64
  int* ip = (int*)(h1 + (size_t)N_NODES * 64);
  int* deg     = ip;                                  // N
  int* rowptr  = deg + N_NODES;                       // N+1
  int* cursor  = rowptr + N_NODES + 1;                // N
  int* csr_src = cursor + N_NODES;                    // E
  int* csr_et  = csr_src + N_EDGES;                   // E
  int* bsum    = csr_et + N_EDGES;                    // 256
  int* boff    = bsum + 256;                          // 256

  // ---- CSR build (graph is shared by both layers) ----
  hipMemsetAsync(deg, 0, N_NODES * sizeof(int), stream);
  hist_kernel<<<(N_EDGES + 255) / 256, 256, 0, stream>>>(dst, deg);
  block_sum_kernel<<<SCAN_B, 256, 0, stream>>>(deg, bsum);
  scan_bsum_kernel<<<1, 256, 0, stream>>>(bsum, boff);
  scan_final_kernel<<<SCAN_B, 256, 0, stream>>>(deg, boff, rowptr, cursor);
  fill_kernel<<<(N_EDGES + 255) / 256, 256, 0, stream>>>(src, dst, etype, cursor, csr_src, csr_et);

  // ================= layer 1 =================
  gemm_xw_alpha<<<(N_NODES + 31) / 32, 256, 0, stream>>>(x, W1, as1, ad1, xs, asrc, adst, N_NODES, IN_DIM);
  relalpha_kernel<<<NREL, 256, 0, stream>>>(rel1, We1, ae1, tab, IN_DIM);
  gat_node_kernel<<<N_NODES, 256, 0, stream>>>(rowptr, csr_src, csr_et, asrc, adst, tab, xs, b1, h1, 1);

  // ================= layer 2 =================
  gemm_xw_alpha<<<(N_NODES + 31) / 32, 256, 0, stream>>>(h1, W2, as2, ad2, xs, asrc, adst, N_NODES, 64);
  relalpha_kernel<<<NREL, 256, 0, stream>>>(rel2, We2, ae2, tab, 64);
  gat_node_kernel<<<N_NODES, 256, 0, stream>>>(rowptr, csr_src, csr_et, asrc, adst, tab, xs, b2, (float*)d_out, 0);
}

// Round 6
// 462.844 us; speedup vs baseline: 3.7544x; 1.0184x over previous
//
#include <hip/hip_runtime.h>
#include <hip/hip_bf16.h>
#include <math.h>

#define N_NODES 50000
#define N_EDGES 800000
#define IN_DIM 128
#define NHEAD 4
#define NREL 64
#define HC 256              // NHEAD * 64 (both layers: H*HID = H*OUT = 256)
#define NEG_SLOPE 0.2f
#define SCAN_B ((N_NODES + 255) / 256)   // 196 blocks

// ============ GEMM + fused alpha: Y = X@W, asrc/adst = per-head dots ============
__global__ __launch_bounds__(256) void gemm_xw_alpha(
    const float* __restrict__ X, const float* __restrict__ W,
    const float* __restrict__ a_s, const float* __restrict__ a_d,
    float* __restrict__ Y, float* __restrict__ asrc, float* __restrict__ adst,
    int M, int K) {
  __shared__ __align__(16) float wlds[32][256];   // [kk][col]
  __shared__ __align__(16) float xlds[32][36];    // [kk][row], padded
  const int t = threadIdx.x;
  const int wv = t >> 6;          // wave id 0..3 -> rows wv*8..wv*8+7
  const int tx = t & 63;          // lane -> cols tx*4..tx*4+3
  const int c4 = tx * 4;
  const int rbase = wv * 8;
  const int row0 = blockIdx.x * 32;

  float acc[8][4];
#pragma unroll
  for (int r = 0; r < 8; ++r)
#pragma unroll
    for (int c = 0; c < 4; ++c) acc[r][c] = 0.f;

  for (int kb = 0; kb < K; kb += 32) {
    __syncthreads();
#pragma unroll
    for (int i = 0; i < 8; ++i) {
      int rr = i * 4 + wv;
      *(float4*)&wlds[rr][c4] = *(const float4*)&W[(size_t)(kb + rr) * HC + c4];
    }
    {
      int r = t >> 3;
      int kk = (t & 7) * 4;
      int row = row0 + r;
      float4 xv = make_float4(0.f, 0.f, 0.f, 0.f);
      if (row < M) xv = *(const float4*)&X[(size_t)row * K + kb + kk];
      xlds[kk + 0][r] = xv.x;
      xlds[kk + 1][r] = xv.y;
      xlds[kk + 2][r] = xv.z;
      xlds[kk + 3][r] = xv.w;
    }
    __syncthreads();
#pragma unroll
    for (int kk = 0; kk < 32; ++kk) {
      const float4 w4 = *(const float4*)&wlds[kk][c4];
      const float4 xa = *(const float4*)&xlds[kk][rbase];
      const float4 xb = *(const float4*)&xlds[kk][rbase + 4];
      const float xr[8] = {xa.x, xa.y, xa.z, xa.w, xb.x, xb.y, xb.z, xb.w};
#pragma unroll
      for (int r = 0; r < 8; ++r) {
        acc[r][0] += xr[r] * w4.x;
        acc[r][1] += xr[r] * w4.y;
        acc[r][2] += xr[r] * w4.z;
        acc[r][3] += xr[r] * w4.w;
      }
    }
  }

  const float4 as4 = *(const float4*)&a_s[c4];
  const float4 ad4 = *(const float4*)&a_d[c4];
  const int h = tx >> 4;          // head owning cols c4..c4+3
#pragma unroll
  for (int r = 0; r < 8; ++r) {
    int row = row0 + rbase + r;
    if (row < M) {
      float4 o = make_float4(acc[r][0], acc[r][1], acc[r][2], acc[r][3]);
      *(float4*)&Y[(size_t)row * HC + c4] = o;
    }
    float sp = acc[r][0] * as4.x + acc[r][1] * as4.y + acc[r][2] * as4.z + acc[r][3] * as4.w;
    float dp = acc[r][0] * ad4.x + acc[r][1] * ad4.y + acc[r][2] * ad4.z + acc[r][3] * ad4.w;
#pragma unroll
    for (int off = 1; off < 16; off <<= 1) {
      sp += __shfl_xor(sp, off);
      dp += __shfl_xor(dp, off);
    }
    if ((tx & 15) == 0 && row < M) {
      asrc[row * NHEAD + h] = sp;
      adst[row * NHEAD + h] = dp;
    }
  }
}

// ============ per-relation alpha_e table [R, H] ============
__global__ __launch_bounds__(256) void relalpha_kernel(
    const float* __restrict__ rel, const float* __restrict__ We,
    const float* __restrict__ a_e, float* __restrict__ tab, int K) {
  int r = blockIdx.x;
  int t = threadIdx.x;  // col in [0,256)
  float acc = 0.f;
  for (int k = 0; k < K; ++k) acc += rel[(size_t)r * K + k] * We[(size_t)k * HC + t];
  int h = t >> 6, lane = t & 63;
  float p = acc * a_e[t];
#pragma unroll
  for (int off = 32; off > 0; off >>= 1) p += __shfl_down(p, off);
  if (lane == 0) tab[r * NHEAD + h] = p;
}

// ============ CSR build ============
__global__ __launch_bounds__(256) void hist_kernel(
    const int* __restrict__ dst, int* __restrict__ deg) {
  int e = blockIdx.x * blockDim.x + threadIdx.x;
  if (e < N_EDGES) atomicAdd(&deg[dst[e]], 1);
}

__global__ __launch_bounds__(256) void block_sum_kernel(
    const int* __restrict__ deg, int* __restrict__ bsum) {
  int i = blockIdx.x * 256 + threadIdx.x;
  int v = (i < N_NODES) ? deg[i] : 0;
#pragma unroll
  for (int off = 32; off > 0; off >>= 1) v += __shfl_down(v, off);
  __shared__ int w[4];
  if ((threadIdx.x & 63) == 0) w[threadIdx.x >> 6] = v;
  __syncthreads();
  if (threadIdx.x == 0) bsum[blockIdx.x] = w[0] + w[1] + w[2] + w[3];
}

__global__ __launch_bounds__(256) void scan_bsum_kernel(
    const int* __restrict__ bsum, int* __restrict__ boff) {
  __shared__ int s[256];
  int t = threadIdx.x;
  int v = (t < SCAN_B) ? bsum[t] : 0;
  s[t] = v;
  __syncthreads();
  for (int off = 1; off < 256; off <<= 1) {
    int u = (t >= off) ? s[t - off] : 0;
    __syncthreads();
    s[t] += u;
    __syncthreads();
  }
  boff[t] = (t == 0) ? 0 : s[t - 1];
}

__global__ __launch_bounds__(256) void scan_final_kernel(
    const int* __restrict__ deg, const int* __restrict__ boff,
    int* __restrict__ rowptr, int* __restrict__ cursor) {
  __shared__ int s[256];
  int t = threadIdx.x;
  int i = blockIdx.x * 256 + t;
  int v = (i < N_NODES) ? deg[i] : 0;
  s[t] = v;
  __syncthreads();
  for (int off = 1; off < 256; off <<= 1) {
    int u = (t >= off) ? s[t - off] : 0;
    __syncthreads();
    s[t] += u;
    __syncthreads();
  }
  int excl = boff[blockIdx.x] + s[t] - v;
  if (i < N_NODES) {
    rowptr[i] = excl;
    cursor[i] = excl;
  }
  if (t == 0 && blockIdx.x == 0) rowptr[N_NODES] = N_EDGES;
}

__global__ __launch_bounds__(256) void fill_kernel(
    const int* __restrict__ src, const int* __restrict__ dst,
    const int* __restrict__ etype, int* __restrict__ cursor,
    int2* __restrict__ csr_pack) {
  int e = blockIdx.x * blockDim.x + threadIdx.x;
  if (e >= N_EDGES) return;
  int d = dst[e];
  int i = atomicAdd(&cursor[d], 1);
  csr_pack[i] = make_int2(src[e], etype[e]);
}

// ============ fused no-max softmax + gather: ONE WAVE PER NODE ============
// w[e,h] = exp(leaky(asrc[s,h]+adst[n,h]+tab[r,h])) computed per-lane;
// acc[lane] covers cols lane*4..lane*4+3 (head = lane>>4); den per-lane.
// No LDS, no __syncthreads; unroll-4 keeps 4 row-gathers in flight.
__global__ __launch_bounds__(256) void gat_node_kernel(
    const int* __restrict__ rowptr, const int2* __restrict__ csr,
    const float* __restrict__ asrc, const float* __restrict__ adst,
    const float* __restrict__ tab, const float* __restrict__ xs,
    const float* __restrict__ b, float* __restrict__ out, int relu) {
  const int n = (blockIdx.x * blockDim.x + threadIdx.x) >> 6;
  if (n >= N_NODES) return;
  const int lane = threadIdx.x & 63;
  const int hh = lane >> 4;               // head of this lane's 4 cols
  const int cbase = lane << 2;
  const int i0 = rowptr[n], i1 = rowptr[n + 1];
  const float adn = adst[n * NHEAD + hh];

  float4 acc = make_float4(0.f, 0.f, 0.f, 0.f);
  float den = 0.f;
  int i = i0;
  for (; i + 4 <= i1; i += 4) {
    const int2 p0 = csr[i], p1 = csr[i + 1], p2 = csr[i + 2], p3 = csr[i + 3];
    float l0 = asrc[p0.x * NHEAD + hh] + adn + tab[p0.y * NHEAD + hh];
    float l1 = asrc[p1.x * NHEAD + hh] + adn + tab[p1.y * NHEAD + hh];
    float l2 = asrc[p2.x * NHEAD + hh] + adn + tab[p2.y * NHEAD + hh];
    float l3 = asrc[p3.x * NHEAD + hh] + adn + tab[p3.y * NHEAD + hh];
    const float4 v0 = *(const float4*)&xs[(size_t)p0.x * HC + cbase];
    const float4 v1 = *(const float4*)&xs[(size_t)p1.x * HC + cbase];
    const float4 v2 = *(const float4*)&xs[(size_t)p2.x * HC + cbase];
    const float4 v3 = *(const float4*)&xs[(size_t)p3.x * HC + cbase];
    l0 = (l0 >= 0.f) ? l0 : NEG_SLOPE * l0;
    l1 = (l1 >= 0.f) ? l1 : NEG_SLOPE * l1;
    l2 = (l2 >= 0.f) ? l2 : NEG_SLOPE * l2;
    l3 = (l3 >= 0.f) ? l3 : NEG_SLOPE * l3;
    const float w0 = __expf(l0), w1 = __expf(l1), w2 = __expf(l2), w3 = __expf(l3);
    den += (w0 + w1) + (w2 + w3);
    acc.x += w0 * v0.x + w1 * v1.x + w2 * v2.x + w3 * v3.x;
    acc.y += w0 * v0.y + w1 * v1.y + w2 * v2.y + w3 * v3.y;
    acc.z += w0 * v0.z + w1 * v1.z + w2 * v2.z + w3 * v3.z;
    acc.w += w0 * v0.w + w1 * v1.w + w2 * v2.w + w3 * v3.w;
  }
  for (; i < i1; ++i) {
    const int2 p = csr[i];
    float l = asrc[p.x * NHEAD + hh] + adn + tab[p.y * NHEAD + hh];
    l = (l >= 0.f) ? l : NEG_SLOPE * l;
    const float w = __expf(l);
    const float4 v = *(const float4*)&xs[(size_t)p.x * HC + cbase];
    den += w;
    acc.x += w * v.x; acc.y += w * v.y; acc.z += w * v.z; acc.w += w * v.w;
  }

  // normalize (fold head-mean 1/4 into reciprocal), then head-sum via shfl
  const float rd = (den > 0.f) ? (0.25f / den) : 0.f;
  float4 y = make_float4(acc.x * rd, acc.y * rd, acc.z * rd, acc.w * rd);
#pragma unroll
  for (int off = 16; off < 64; off <<= 1) {
    y.x += __shfl_xor(y.x, off);
    y.y += __shfl_xor(y.y, off);
    y.z += __shfl_xor(y.z, off);
    y.w += __shfl_xor(y.w, off);
  }
  if (lane < 16) {
    const float4 bb = *(const float4*)&b[lane * 4];
    y.x += bb.x; y.y += bb.y; y.z += bb.z; y.w += bb.w;
    if (relu) {
      y.x = fmaxf(y.x, 0.f); y.y = fmaxf(y.y, 0.f);
      y.z = fmaxf(y.z, 0.f); y.w = fmaxf(y.w, 0.f);
    }
    *(float4*)&out[(size_t)n * 64 + lane * 4] = y;
  }
}

extern "C" void kernel_launch(void* const* d_in, const int* in_sizes, int n_in,
                              void* d_out, int out_size, void* d_ws, size_t ws_size,
                              hipStream_t stream) {
  const float* x   = (const float*)d_in[0];
  const int* eidx  = (const int*)d_in[1];
  const int* etype = (const int*)d_in[2];
  const float* rel1 = (const float*)d_in[3];
  const float* W1   = (const float*)d_in[4];
  const float* We1  = (const float*)d_in[5];
  const float* as1  = (const float*)d_in[6];
  const float* ad1  = (const float*)d_in[7];
  const float* ae1  = (const float*)d_in[8];
  const float* b1   = (const float*)d_in[9];
  const float* rel2 = (const float*)d_in[10];
  const float* W2   = (const float*)d_in[11];
  const float* We2  = (const float*)d_in[12];
  const float* as2  = (const float*)d_in[13];
  const float* ad2  = (const float*)d_in[14];
  const float* ae2  = (const float*)d_in[15];
  const float* b2   = (const float*)d_in[16];
  const int* src = eidx;
  const int* dst = eidx + N_EDGES;

  // ---- workspace layout ----
  float* ws = (float*)d_ws;
  float* xs   = ws;                                   // N*256
  float* asrc = xs + (size_t)N_NODES * HC;            // N*4
  float* adst = asrc + (size_t)N_NODES * NHEAD;       // N*4
  float* tab  = adst + (size_t)N_NODES * NHEAD;       // R*4
  float* h1   = tab + NREL * NHEAD;                   // N*64
  int* ip = (int*)(h1 + (size_t)N_NODES * 64);
  int* deg     = ip;                                  // N
  int* rowptr  = deg + N_NODES;                       // N+1
  int* cursor  = rowptr + N_NODES + 1;                // N
  int2* csr    = (int2*)(cursor + N_NODES + 1);       // E int2 (8B aligned)
  int* bsum    = (int*)(csr + N_EDGES);               // 256
  int* boff    = bsum + 256;                          // 256

  // ---- CSR build (graph is shared by both layers) ----
  hipMemsetAsync(deg, 0, N_NODES * sizeof(int), stream);
  hist_kernel<<<(N_EDGES + 255) / 256, 256, 0, stream>>>(dst, deg);
  block_sum_kernel<<<SCAN_B, 256, 0, stream>>>(deg, bsum);
  scan_bsum_kernel<<<1, 256, 0, stream>>>(bsum, boff);
  scan_final_kernel<<<SCAN_B, 256, 0, stream>>>(deg, boff, rowptr, cursor);
  fill_kernel<<<(N_EDGES + 255) / 256, 256, 0, stream>>>(src, dst, etype, cursor, csr);

  const int GB = (N_NODES * 64 + 255) / 256;   // one wave per node

  // ================= layer 1 =================
  gemm_xw_alpha<<<(N_NODES + 31) / 32, 256, 0, stream>>>(x, W1, as1, ad1, xs, asrc, adst, N_NODES, IN_DIM);
  relalpha_kernel<<<NREL, 256, 0, stream>>>(rel1, We1, ae1, tab, IN_DIM);
  gat_node_kernel<<<GB, 256, 0, stream>>>(rowptr, csr, asrc, adst, tab, xs, b1, h1, 1);

  // ================= layer 2 =================
  gemm_xw_alpha<<<(N_NODES + 31) / 32, 256, 0, stream>>>(h1, W2, as2, ad2, xs, asrc, adst, N_NODES, 64);
  relalpha_kernel<<<NREL, 256, 0, stream>>>(rel2, We2, ae2, tab, 64);
  gat_node_kernel<<<GB, 256, 0, stream>>>(rowptr, csr, asrc, adst, tab, xs, b2, (float*)d_out, 0);
}

// Round 7
// 361.926 us; speedup vs baseline: 4.8013x; 1.2788x over previous
//
#include <hip/hip_runtime.h>
#include <hip/hip_bf16.h>
#include <hip/hip_fp16.h>
#include <math.h>

#define N_NODES 50000
#define N_EDGES 800000
#define IN_DIM 128
#define NHEAD 4
#define NREL 64
#define HC 256              // NHEAD * 64 (both layers: H*HID = H*OUT = 256)
#define NEG_SLOPE 0.2f
#define SCAN_B ((N_NODES + 255) / 256)   // 196 blocks

// ============ GEMM + fused alpha: xs16 = fp16(X@W), asrc/adst fp32 ============
__global__ __launch_bounds__(256) void gemm_xw_alpha(
    const float* __restrict__ X, const float* __restrict__ W,
    const float* __restrict__ a_s, const float* __restrict__ a_d,
    __half2* __restrict__ xs16, float* __restrict__ asrc, float* __restrict__ adst,
    int M, int K) {
  __shared__ __align__(16) float wlds[32][256];   // [kk][col]
  __shared__ __align__(16) float xlds[32][36];    // [kk][row], padded
  const int t = threadIdx.x;
  const int wv = t >> 6;          // wave id 0..3 -> rows wv*8..wv*8+7
  const int tx = t & 63;          // lane -> cols tx*4..tx*4+3
  const int c4 = tx * 4;
  const int rbase = wv * 8;
  const int row0 = blockIdx.x * 32;

  float acc[8][4];
#pragma unroll
  for (int r = 0; r < 8; ++r)
#pragma unroll
    for (int c = 0; c < 4; ++c) acc[r][c] = 0.f;

  for (int kb = 0; kb < K; kb += 32) {
    __syncthreads();
#pragma unroll
    for (int i = 0; i < 8; ++i) {
      int rr = i * 4 + wv;
      *(float4*)&wlds[rr][c4] = *(const float4*)&W[(size_t)(kb + rr) * HC + c4];
    }
    {
      int r = t >> 3;
      int kk = (t & 7) * 4;
      int row = row0 + r;
      float4 xv = make_float4(0.f, 0.f, 0.f, 0.f);
      if (row < M) xv = *(const float4*)&X[(size_t)row * K + kb + kk];
      xlds[kk + 0][r] = xv.x;
      xlds[kk + 1][r] = xv.y;
      xlds[kk + 2][r] = xv.z;
      xlds[kk + 3][r] = xv.w;
    }
    __syncthreads();
#pragma unroll
    for (int kk = 0; kk < 32; ++kk) {
      const float4 w4 = *(const float4*)&wlds[kk][c4];
      const float4 xa = *(const float4*)&xlds[kk][rbase];
      const float4 xb = *(const float4*)&xlds[kk][rbase + 4];
      const float xr[8] = {xa.x, xa.y, xa.z, xa.w, xb.x, xb.y, xb.z, xb.w};
#pragma unroll
      for (int r = 0; r < 8; ++r) {
        acc[r][0] += xr[r] * w4.x;
        acc[r][1] += xr[r] * w4.y;
        acc[r][2] += xr[r] * w4.z;
        acc[r][3] += xr[r] * w4.w;
      }
    }
  }

  const float4 as4 = *(const float4*)&a_s[c4];
  const float4 ad4 = *(const float4*)&a_d[c4];
  const int h = tx >> 4;          // head owning cols c4..c4+3
#pragma unroll
  for (int r = 0; r < 8; ++r) {
    int row = row0 + rbase + r;
    if (row < M) {
      __half2 q0 = __floats2half2_rn(acc[r][0], acc[r][1]);
      __half2 q1 = __floats2half2_rn(acc[r][2], acc[r][3]);
      __half2* p = &xs16[((size_t)row * HC + c4) >> 1];
      p[0] = q0;
      p[1] = q1;
    }
    float sp = acc[r][0] * as4.x + acc[r][1] * as4.y + acc[r][2] * as4.z + acc[r][3] * as4.w;
    float dp = acc[r][0] * ad4.x + acc[r][1] * ad4.y + acc[r][2] * ad4.z + acc[r][3] * ad4.w;
#pragma unroll
    for (int off = 1; off < 16; off <<= 1) {
      sp += __shfl_xor(sp, off);
      dp += __shfl_xor(dp, off);
    }
    if ((tx & 15) == 0 && row < M) {
      asrc[row * NHEAD + h] = sp;
      adst[row * NHEAD + h] = dp;
    }
  }
}

// ============ per-relation alpha_e table [R, H] ============
__global__ __launch_bounds__(256) void relalpha_kernel(
    const float* __restrict__ rel, const float* __restrict__ We,
    const float* __restrict__ a_e, float* __restrict__ tab, int K) {
  int r = blockIdx.x;
  int t = threadIdx.x;  // col in [0,256)
  float acc = 0.f;
  for (int k = 0; k < K; ++k) acc += rel[(size_t)r * K + k] * We[(size_t)k * HC + t];
  int h = t >> 6, lane = t & 63;
  float p = acc * a_e[t];
#pragma unroll
  for (int off = 32; off > 0; off >>= 1) p += __shfl_down(p, off);
  if (lane == 0) tab[r * NHEAD + h] = p;
}

// ============ CSR build ============
__global__ __launch_bounds__(256) void hist_kernel(
    const int* __restrict__ dst, int* __restrict__ deg) {
  int e = blockIdx.x * blockDim.x + threadIdx.x;
  if (e < N_EDGES) atomicAdd(&deg[dst[e]], 1);
}

__global__ __launch_bounds__(256) void block_sum_kernel(
    const int* __restrict__ deg, int* __restrict__ bsum) {
  int i = blockIdx.x * 256 + threadIdx.x;
  int v = (i < N_NODES) ? deg[i] : 0;
#pragma unroll
  for (int off = 32; off > 0; off >>= 1) v += __shfl_down(v, off);
  __shared__ int w[4];
  if ((threadIdx.x & 63) == 0) w[threadIdx.x >> 6] = v;
  __syncthreads();
  if (threadIdx.x == 0) bsum[blockIdx.x] = w[0] + w[1] + w[2] + w[3];
}

__global__ __launch_bounds__(256) void scan_bsum_kernel(
    const int* __restrict__ bsum, int* __restrict__ boff) {
  __shared__ int s[256];
  int t = threadIdx.x;
  int v = (t < SCAN_B) ? bsum[t] : 0;
  s[t] = v;
  __syncthreads();
  for (int off = 1; off < 256; off <<= 1) {
    int u = (t >= off) ? s[t - off] : 0;
    __syncthreads();
    s[t] += u;
    __syncthreads();
  }
  boff[t] = (t == 0) ? 0 : s[t - 1];
}

__global__ __launch_bounds__(256) void scan_final_kernel(
    const int* __restrict__ deg, const int* __restrict__ boff,
    int* __restrict__ rowptr, int* __restrict__ cursor) {
  __shared__ int s[256];
  int t = threadIdx.x;
  int i = blockIdx.x * 256 + t;
  int v = (i < N_NODES) ? deg[i] : 0;
  s[t] = v;
  __syncthreads();
  for (int off = 1; off < 256; off <<= 1) {
    int u = (t >= off) ? s[t - off] : 0;
    __syncthreads();
    s[t] += u;
    __syncthreads();
  }
  int excl = boff[blockIdx.x] + s[t] - v;
  if (i < N_NODES) {
    rowptr[i] = excl;
    cursor[i] = excl;
  }
  if (t == 0 && blockIdx.x == 0) rowptr[N_NODES] = N_EDGES;
}

__global__ __launch_bounds__(256) void fill_kernel(
    const int* __restrict__ src, const int* __restrict__ dst,
    const int* __restrict__ etype, int* __restrict__ cursor,
    int2* __restrict__ csr_pack) {
  int e = blockIdx.x * blockDim.x + threadIdx.x;
  if (e >= N_EDGES) return;
  int d = dst[e];
  int i = atomicAdd(&cursor[d], 1);
  csr_pack[i] = make_int2(src[e], etype[e]);
}

// ============ fused no-max softmax + fp16 gather: ONE WAVE PER NODE ============
// tab lives in a register: lane L holds tab[rel=L][head=hh]; lookup via __shfl.
__global__ __launch_bounds__(256) void gat_node_kernel(
    const int* __restrict__ rowptr, const int2* __restrict__ csr,
    const float* __restrict__ asrc, const float* __restrict__ adst,
    const float* __restrict__ tab, const __half2* __restrict__ xs16,
    const float* __restrict__ b, float* __restrict__ out, int relu) {
  const int n = (blockIdx.x * blockDim.x + threadIdx.x) >> 6;
  if (n >= N_NODES) return;
  const int lane = threadIdx.x & 63;
  const int hh = lane >> 4;               // head of this lane's 4 cols
  const int cbase = lane << 2;            // col base (in halves); /2 for half2 idx
  const int i0 = rowptr[n], i1 = rowptr[n + 1];
  const float adn = adst[n * NHEAD + hh];
  const float treg = tab[lane * NHEAD + hh];   // lane=rel id (NREL==64)

  float4 acc = make_float4(0.f, 0.f, 0.f, 0.f);
  float den = 0.f;
  int i = i0;
  for (; i + 4 <= i1; i += 4) {
    const int2 p0 = csr[i], p1 = csr[i + 1], p2 = csr[i + 2], p3 = csr[i + 3];
    float l0 = asrc[p0.x * NHEAD + hh] + adn + __shfl(treg, p0.y);
    float l1 = asrc[p1.x * NHEAD + hh] + adn + __shfl(treg, p1.y);
    float l2 = asrc[p2.x * NHEAD + hh] + adn + __shfl(treg, p2.y);
    float l3 = asrc[p3.x * NHEAD + hh] + adn + __shfl(treg, p3.y);
    const __half2* r0 = &xs16[((size_t)p0.x * HC + cbase) >> 1];
    const __half2* r1 = &xs16[((size_t)p1.x * HC + cbase) >> 1];
    const __half2* r2 = &xs16[((size_t)p2.x * HC + cbase) >> 1];
    const __half2* r3 = &xs16[((size_t)p3.x * HC + cbase) >> 1];
    const uint2 q0 = *(const uint2*)r0;
    const uint2 q1 = *(const uint2*)r1;
    const uint2 q2 = *(const uint2*)r2;
    const uint2 q3 = *(const uint2*)r3;
    l0 = (l0 >= 0.f) ? l0 : NEG_SLOPE * l0;
    l1 = (l1 >= 0.f) ? l1 : NEG_SLOPE * l1;
    l2 = (l2 >= 0.f) ? l2 : NEG_SLOPE * l2;
    l3 = (l3 >= 0.f) ? l3 : NEG_SLOPE * l3;
    const float w0 = __expf(l0), w1 = __expf(l1), w2 = __expf(l2), w3 = __expf(l3);
    den += (w0 + w1) + (w2 + w3);
    const float2 a0 = __half22float2(*(const __half2*)&q0.x), b0 = __half22float2(*(const __half2*)&q0.y);
    const float2 a1 = __half22float2(*(const __half2*)&q1.x), b1 = __half22float2(*(const __half2*)&q1.y);
    const float2 a2 = __half22float2(*(const __half2*)&q2.x), b2 = __half22float2(*(const __half2*)&q2.y);
    const float2 a3 = __half22float2(*(const __half2*)&q3.x), b3 = __half22float2(*(const __half2*)&q3.y);
    acc.x += w0 * a0.x + w1 * a1.x + w2 * a2.x + w3 * a3.x;
    acc.y += w0 * a0.y + w1 * a1.y + w2 * a2.y + w3 * a3.y;
    acc.z += w0 * b0.x + w1 * b1.x + w2 * b2.x + w3 * b3.x;
    acc.w += w0 * b0.y + w1 * b1.y + w2 * b2.y + w3 * b3.y;
  }
  for (; i < i1; ++i) {
    const int2 p = csr[i];
    float l = asrc[p.x * NHEAD + hh] + adn + __shfl(treg, p.y);
    l = (l >= 0.f) ? l : NEG_SLOPE * l;
    const float w = __expf(l);
    const uint2 q = *(const uint2*)&xs16[((size_t)p.x * HC + cbase) >> 1];
    const float2 a = __half22float2(*(const __half2*)&q.x);
    const float2 c = __half22float2(*(const __half2*)&q.y);
    den += w;
    acc.x += w * a.x; acc.y += w * a.y; acc.z += w * c.x; acc.w += w * c.y;
  }

  // normalize (fold head-mean 1/4 into reciprocal), then head-sum via shfl
  const float rd = (den > 0.f) ? (0.25f / den) : 0.f;
  float4 y = make_float4(acc.x * rd, acc.y * rd, acc.z * rd, acc.w * rd);
#pragma unroll
  for (int off = 16; off < 64; off <<= 1) {
    y.x += __shfl_xor(y.x, off);
    y.y += __shfl_xor(y.y, off);
    y.z += __shfl_xor(y.z, off);
    y.w += __shfl_xor(y.w, off);
  }
  if (lane < 16) {
    const float4 bb = *(const float4*)&b[lane * 4];
    y.x += bb.x; y.y += bb.y; y.z += bb.z; y.w += bb.w;
    if (relu) {
      y.x = fmaxf(y.x, 0.f); y.y = fmaxf(y.y, 0.f);
      y.z = fmaxf(y.z, 0.f); y.w = fmaxf(y.w, 0.f);
    }
    *(float4*)&out[(size_t)n * 64 + lane * 4] = y;
  }
}

extern "C" void kernel_launch(void* const* d_in, const int* in_sizes, int n_in,
                              void* d_out, int out_size, void* d_ws, size_t ws_size,
                              hipStream_t stream) {
  const float* x   = (const float*)d_in[0];
  const int* eidx  = (const int*)d_in[1];
  const int* etype = (const int*)d_in[2];
  const float* rel1 = (const float*)d_in[3];
  const float* W1   = (const float*)d_in[4];
  const float* We1  = (const float*)d_in[5];
  const float* as1  = (const float*)d_in[6];
  const float* ad1  = (const float*)d_in[7];
  const float* ae1  = (const float*)d_in[8];
  const float* b1   = (const float*)d_in[9];
  const float* rel2 = (const float*)d_in[10];
  const float* W2   = (const float*)d_in[11];
  const float* We2  = (const float*)d_in[12];
  const float* as2  = (const float*)d_in[13];
  const float* ad2  = (const float*)d_in[14];
  const float* ae2  = (const float*)d_in[15];
  const float* b2   = (const float*)d_in[16];
  const int* src = eidx;
  const int* dst = eidx + N_EDGES;

  // ---- workspace layout ----
  __half2* xs16 = (__half2*)d_ws;                         // N*256 halves = N*128 half2
  float* fbase = (float*)((char*)d_ws + (size_t)N_NODES * HC * 2);
  float* asrc = fbase;                                    // N*4
  float* adst = asrc + (size_t)N_NODES * NHEAD;           // N*4
  float* tab  = adst + (size_t)N_NODES * NHEAD;           // R*4
  float* h1   = tab + NREL * NHEAD;                       // N*64
  int* ip = (int*)(h1 + (size_t)N_NODES * 64);
  int* deg     = ip;                                      // N
  int* rowptr  = deg + N_NODES;                           // N+1
  int* cursor  = rowptr + N_NODES + 1;                    // N
  int2* csr    = (int2*)(cursor + N_NODES + 1);           // E int2 (8B aligned)
  int* bsum    = (int*)(csr + N_EDGES);                   // 256
  int* boff    = bsum + 256;                              // 256

  // ---- CSR build (graph is shared by both layers) ----
  hipMemsetAsync(deg, 0, N_NODES * sizeof(int), stream);
  hist_kernel<<<(N_EDGES + 255) / 256, 256, 0, stream>>>(dst, deg);
  block_sum_kernel<<<SCAN_B, 256, 0, stream>>>(deg, bsum);
  scan_bsum_kernel<<<1, 256, 0, stream>>>(bsum, boff);
  scan_final_kernel<<<SCAN_B, 256, 0, stream>>>(deg, boff, rowptr, cursor);
  fill_kernel<<<(N_EDGES + 255) / 256, 256, 0, stream>>>(src, dst, etype, cursor, csr);

  const int GB = (N_NODES * 64 + 255) / 256;   // one wave per node

  // ================= layer 1 =================
  gemm_xw_alpha<<<(N_NODES + 31) / 32, 256, 0, stream>>>(x, W1, as1, ad1, xs16, asrc, adst, N_NODES, IN_DIM);
  relalpha_kernel<<<NREL, 256, 0, stream>>>(rel1, We1, ae1, tab, IN_DIM);
  gat_node_kernel<<<GB, 256, 0, stream>>>(rowptr, csr, asrc, adst, tab, xs16, b1, h1, 1);

  // ================= layer 2 =================
  gemm_xw_alpha<<<(N_NODES + 31) / 32, 256, 0, stream>>>(h1, W2, as2, ad2, xs16, asrc, adst, N_NODES, 64);
  relalpha_kernel<<<NREL, 256, 0, stream>>>(rel2, We2, ae2, tab, 64);
  gat_node_kernel<<<GB, 256, 0, stream>>>(rowptr, csr, asrc, adst, tab, xs16, b2, (float*)d_out, 0);
}

// Round 8
// 353.263 us; speedup vs baseline: 4.9191x; 1.0245x over previous
//
#include <hip/hip_runtime.h>
#include <hip/hip_bf16.h>
#include <hip/hip_fp16.h>
#include <math.h>

#define N_NODES 50000
#define N_EDGES 800000
#define IN_DIM 128
#define NHEAD 4
#define NREL 64
#define HC 256              // NHEAD * 64 (both layers: H*HID = H*OUT = 256)
#define NEG_SLOPE 0.2f
#define SCAN_B ((N_NODES + 255) / 256)   // 196 blocks
#define PADR 132            // LDS row pad (floats)

// ============ GEMM + fused alpha, 128x128 tile, 16x4 per thread ============
// Y(fp16) = X@W ; asrc/adst = per-head dots of fp32 accumulators.
// Grid: (ceil(M/128), 2). Col-block cb covers cols cb*128.. and heads {2cb,2cb+1}.
__global__ __launch_bounds__(256) void gemm_xw_alpha(
    const float* __restrict__ X, const float* __restrict__ W,
    const float* __restrict__ a_s, const float* __restrict__ a_d,
    __half2* __restrict__ xs16, float* __restrict__ asrc, float* __restrict__ adst,
    int M, int K) {
  __shared__ __align__(16) float xlds[32][PADR];   // [kk][row] (transposed)
  __shared__ __align__(16) float wlds[32][PADR];   // [kk][col]
  const int t = threadIdx.x;
  const int wv = t >> 6;
  const int l = t & 63;
  const int rg = l >> 5;                  // row-half within wave
  const int cg = l & 31;                  // col-group
  const int cc = cg * 4;                  // local col
  const int rbase = wv * 32 + rg * 16;    // local row base (16 rows per thread)
  const int row0 = blockIdx.x * 128;
  const int c0 = blockIdx.y * 128;        // global col base

  float acc[16][4];
#pragma unroll
  for (int r = 0; r < 16; ++r)
#pragma unroll
    for (int c = 0; c < 4; ++c) acc[r][c] = 0.f;

  for (int kb = 0; kb < K; kb += 32) {
    __syncthreads();
    // stage W tile: 32 kk x 128 cols
#pragma unroll
    for (int p = 0; p < 4; ++p) {
      int kk = (t >> 5) + p * 8;
      int c4 = (t & 31) * 4;
      *(float4*)&wlds[kk][c4] = *(const float4*)&W[(size_t)(kb + kk) * HC + c0 + c4];
    }
    // stage X tile transposed: 128 rows x 32 kk
#pragma unroll
    for (int p = 0; p < 4; ++p) {
      int r = (t >> 3) + p * 32;
      int kks = (t & 7) * 4;
      int row = row0 + r;
      float4 xv = make_float4(0.f, 0.f, 0.f, 0.f);
      if (row < M) xv = *(const float4*)&X[(size_t)row * K + kb + kks];
      xlds[kks + 0][r] = xv.x;
      xlds[kks + 1][r] = xv.y;
      xlds[kks + 2][r] = xv.z;
      xlds[kks + 3][r] = xv.w;
    }
    __syncthreads();
#pragma unroll 8
    for (int kk = 0; kk < 32; ++kk) {
      const float4 w4 = *(const float4*)&wlds[kk][cc];
      const float4 xa = *(const float4*)&xlds[kk][rbase];
      const float4 xb = *(const float4*)&xlds[kk][rbase + 4];
      const float4 xc = *(const float4*)&xlds[kk][rbase + 8];
      const float4 xd = *(const float4*)&xlds[kk][rbase + 12];
      const float xr[16] = {xa.x, xa.y, xa.z, xa.w, xb.x, xb.y, xb.z, xb.w,
                            xc.x, xc.y, xc.z, xc.w, xd.x, xd.y, xd.z, xd.w};
#pragma unroll
      for (int r = 0; r < 16; ++r) {
        acc[r][0] += xr[r] * w4.x;
        acc[r][1] += xr[r] * w4.y;
        acc[r][2] += xr[r] * w4.z;
        acc[r][3] += xr[r] * w4.w;
      }
    }
  }

  const float4 as4 = *(const float4*)&a_s[c0 + cc];
  const float4 ad4 = *(const float4*)&a_d[c0 + cc];
  const int head = blockIdx.y * 2 + (cg >> 4);
#pragma unroll
  for (int r = 0; r < 16; ++r) {
    const int row = row0 + rbase + r;
    const bool ok = row < M;
    if (ok) {
      __half2 q0 = __floats2half2_rn(acc[r][0], acc[r][1]);
      __half2 q1 = __floats2half2_rn(acc[r][2], acc[r][3]);
      uint2 qq = make_uint2(*(unsigned*)&q0, *(unsigned*)&q1);
      *(uint2*)&xs16[((size_t)row * HC + c0 + cc) >> 1] = qq;
    }
    float sp = acc[r][0] * as4.x + acc[r][1] * as4.y + acc[r][2] * as4.z + acc[r][3] * as4.w;
    float dp = acc[r][0] * ad4.x + acc[r][1] * ad4.y + acc[r][2] * ad4.z + acc[r][3] * ad4.w;
#pragma unroll
    for (int off = 1; off < 16; off <<= 1) {
      sp += __shfl_xor(sp, off);
      dp += __shfl_xor(dp, off);
    }
    if ((cg & 15) == 0 && ok) {
      asrc[row * NHEAD + head] = sp;
      adst[row * NHEAD + head] = dp;
    }
  }
}

// ============ per-relation alpha_e tables for BOTH layers ============
__global__ __launch_bounds__(256) void relalpha2_kernel(
    const float* __restrict__ rel1, const float* __restrict__ We1, const float* __restrict__ ae1,
    const float* __restrict__ rel2, const float* __restrict__ We2, const float* __restrict__ ae2,
    float* __restrict__ tab1, float* __restrict__ tab2) {
  const int layer = blockIdx.x >> 6;
  const int r = blockIdx.x & 63;
  const float* rel = layer ? rel2 : rel1;
  const float* We  = layer ? We2  : We1;
  const float* ae  = layer ? ae2  : ae1;
  float* tab       = layer ? tab2 : tab1;
  const int K      = layer ? 64   : IN_DIM;
  int t = threadIdx.x;
  float acc = 0.f;
  for (int k = 0; k < K; ++k) acc += rel[(size_t)r * K + k] * We[(size_t)k * HC + t];
  int h = t >> 6, lane = t & 63;
  float p = acc * ae[t];
#pragma unroll
  for (int off = 32; off > 0; off >>= 1) p += __shfl_down(p, off);
  if (lane == 0) tab[r * NHEAD + h] = p;
}

// ============ CSR build ============
__global__ __launch_bounds__(256) void hist_kernel(
    const int* __restrict__ dst, int* __restrict__ deg) {
  int e = blockIdx.x * blockDim.x + threadIdx.x;
  if (e < N_EDGES) atomicAdd(&deg[dst[e]], 1);
}

__global__ __launch_bounds__(256) void block_sum_kernel(
    const int* __restrict__ deg, int* __restrict__ bsum) {
  int i = blockIdx.x * 256 + threadIdx.x;
  int v = (i < N_NODES) ? deg[i] : 0;
#pragma unroll
  for (int off = 32; off > 0; off >>= 1) v += __shfl_down(v, off);
  __shared__ int w[4];
  if ((threadIdx.x & 63) == 0) w[threadIdx.x >> 6] = v;
  __syncthreads();
  if (threadIdx.x == 0) bsum[blockIdx.x] = w[0] + w[1] + w[2] + w[3];
}

__global__ __launch_bounds__(256) void scan_bsum_kernel(
    const int* __restrict__ bsum, int* __restrict__ boff) {
  __shared__ int s[256];
  int t = threadIdx.x;
  int v = (t < SCAN_B) ? bsum[t] : 0;
  s[t] = v;
  __syncthreads();
  for (int off = 1; off < 256; off <<= 1) {
    int u = (t >= off) ? s[t - off] : 0;
    __syncthreads();
    s[t] += u;
    __syncthreads();
  }
  boff[t] = (t == 0) ? 0 : s[t - 1];
}

__global__ __launch_bounds__(256) void scan_final_kernel(
    const int* __restrict__ deg, const int* __restrict__ boff,
    int* __restrict__ rowptr, int* __restrict__ cursor) {
  __shared__ int s[256];
  int t = threadIdx.x;
  int i = blockIdx.x * 256 + t;
  int v = (i < N_NODES) ? deg[i] : 0;
  s[t] = v;
  __syncthreads();
  for (int off = 1; off < 256; off <<= 1) {
    int u = (t >= off) ? s[t - off] : 0;
    __syncthreads();
    s[t] += u;
    __syncthreads();
  }
  int excl = boff[blockIdx.x] + s[t] - v;
  if (i < N_NODES) {
    rowptr[i] = excl;
    cursor[i] = excl;
  }
  if (t == 0 && blockIdx.x == 0) rowptr[N_NODES] = N_EDGES;
}

__global__ __launch_bounds__(256) void fill_kernel(
    const int* __restrict__ src, const int* __restrict__ dst,
    const int* __restrict__ etype, int* __restrict__ cursor,
    int2* __restrict__ csr_pack) {
  int e = blockIdx.x * blockDim.x + threadIdx.x;
  if (e >= N_EDGES) return;
  int d = dst[e];
  int i = atomicAdd(&cursor[d], 1);
  csr_pack[i] = make_int2(src[e], etype[e]);
}

// ============ fused no-max softmax + fp16 gather: ONE WAVE PER NODE ============
__global__ __launch_bounds__(256) void gat_node_kernel(
    const int* __restrict__ rowptr, const int2* __restrict__ csr,
    const float* __restrict__ asrc, const float* __restrict__ adst,
    const float* __restrict__ tab, const __half2* __restrict__ xs16,
    const float* __restrict__ b, float* __restrict__ out, int relu) {
  const int n = (blockIdx.x * blockDim.x + threadIdx.x) >> 6;
  if (n >= N_NODES) return;
  const int lane = threadIdx.x & 63;
  const int hh = lane >> 4;               // head of this lane's 4 cols
  const int cbase = lane << 2;
  const int i0 = rowptr[n], i1 = rowptr[n + 1];
  const float adn = adst[n * NHEAD + hh];
  const float treg = tab[lane * NHEAD + hh];   // lane = rel id (NREL==64)

  float4 acc = make_float4(0.f, 0.f, 0.f, 0.f);
  float den = 0.f;
  int i = i0;
  for (; i + 4 <= i1; i += 4) {
    const int2 p0 = csr[i], p1 = csr[i + 1], p2 = csr[i + 2], p3 = csr[i + 3];
    float l0 = asrc[p0.x * NHEAD + hh] + adn + __shfl(treg, p0.y);
    float l1 = asrc[p1.x * NHEAD + hh] + adn + __shfl(treg, p1.y);
    float l2 = asrc[p2.x * NHEAD + hh] + adn + __shfl(treg, p2.y);
    float l3 = asrc[p3.x * NHEAD + hh] + adn + __shfl(treg, p3.y);
    const uint2 q0 = *(const uint2*)&xs16[((size_t)p0.x * HC + cbase) >> 1];
    const uint2 q1 = *(const uint2*)&xs16[((size_t)p1.x * HC + cbase) >> 1];
    const uint2 q2 = *(const uint2*)&xs16[((size_t)p2.x * HC + cbase) >> 1];
    const uint2 q3 = *(const uint2*)&xs16[((size_t)p3.x * HC + cbase) >> 1];
    l0 = (l0 >= 0.f) ? l0 : NEG_SLOPE * l0;
    l1 = (l1 >= 0.f) ? l1 : NEG_SLOPE * l1;
    l2 = (l2 >= 0.f) ? l2 : NEG_SLOPE * l2;
    l3 = (l3 >= 0.f) ? l3 : NEG_SLOPE * l3;
    const float w0 = __expf(l0), w1 = __expf(l1), w2 = __expf(l2), w3 = __expf(l3);
    den += (w0 + w1) + (w2 + w3);
    const float2 a0 = __half22float2(*(const __half2*)&q0.x), b0 = __half22float2(*(const __half2*)&q0.y);
    const float2 a1 = __half22float2(*(const __half2*)&q1.x), b1 = __half22float2(*(const __half2*)&q1.y);
    const float2 a2 = __half22float2(*(const __half2*)&q2.x), b2 = __half22float2(*(const __half2*)&q2.y);
    const float2 a3 = __half22float2(*(const __half2*)&q3.x), b3 = __half22float2(*(const __half2*)&q3.y);
    acc.x += w0 * a0.x + w1 * a1.x + w2 * a2.x + w3 * a3.x;
    acc.y += w0 * a0.y + w1 * a1.y + w2 * a2.y + w3 * a3.y;
    acc.z += w0 * b0.x + w1 * b1.x + w2 * b2.x + w3 * b3.x;
    acc.w += w0 * b0.y + w1 * b1.y + w2 * b2.y + w3 * b3.y;
  }
  for (; i < i1; ++i) {
    const int2 p = csr[i];
    float l = asrc[p.x * NHEAD + hh] + adn + __shfl(treg, p.y);
    l = (l >= 0.f) ? l : NEG_SLOPE * l;
    const float w = __expf(l);
    const uint2 q = *(const uint2*)&xs16[((size_t)p.x * HC + cbase) >> 1];
    const float2 a = __half22float2(*(const __half2*)&q.x);
    const float2 c = __half22float2(*(const __half2*)&q.y);
    den += w;
    acc.x += w * a.x; acc.y += w * a.y; acc.z += w * c.x; acc.w += w * c.y;
  }

  const float rd = (den > 0.f) ? (0.25f / den) : 0.f;
  float4 y = make_float4(acc.x * rd, acc.y * rd, acc.z * rd, acc.w * rd);
#pragma unroll
  for (int off = 16; off < 64; off <<= 1) {
    y.x += __shfl_xor(y.x, off);
    y.y += __shfl_xor(y.y, off);
    y.z += __shfl_xor(y.z, off);
    y.w += __shfl_xor(y.w, off);
  }
  if (lane < 16) {
    const float4 bb = *(const float4*)&b[lane * 4];
    y.x += bb.x; y.y += bb.y; y.z += bb.z; y.w += bb.w;
    if (relu) {
      y.x = fmaxf(y.x, 0.f); y.y = fmaxf(y.y, 0.f);
      y.z = fmaxf(y.z, 0.f); y.w = fmaxf(y.w, 0.f);
    }
    *(float4*)&out[(size_t)n * 64 + lane * 4] = y;
  }
}

extern "C" void kernel_launch(void* const* d_in, const int* in_sizes, int n_in,
                              void* d_out, int out_size, void* d_ws, size_t ws_size,
                              hipStream_t stream) {
  const float* x   = (const float*)d_in[0];
  const int* eidx  = (const int*)d_in[1];
  const int* etype = (const int*)d_in[2];
  const float* rel1 = (const float*)d_in[3];
  const float* W1   = (const float*)d_in[4];
  const float* We1  = (const float*)d_in[5];
  const float* as1  = (const float*)d_in[6];
  const float* ad1  = (const float*)d_in[7];
  const float* ae1  = (const float*)d_in[8];
  const float* b1   = (const float*)d_in[9];
  const float* rel2 = (const float*)d_in[10];
  const float* W2   = (const float*)d_in[11];
  const float* We2  = (const float*)d_in[12];
  const float* as2  = (const float*)d_in[13];
  const float* ad2  = (const float*)d_in[14];
  const float* ae2  = (const float*)d_in[15];
  const float* b2   = (const float*)d_in[16];
  const int* src = eidx;
  const int* dst = eidx + N_EDGES;

  // ---- workspace layout ----
  __half2* xs16 = (__half2*)d_ws;                         // N*256 halves
  float* fbase = (float*)((char*)d_ws + (size_t)N_NODES * HC * 2);
  float* asrc = fbase;                                    // N*4
  float* adst = asrc + (size_t)N_NODES * NHEAD;           // N*4
  float* tab1 = adst + (size_t)N_NODES * NHEAD;           // R*4
  float* tab2 = tab1 + NREL * NHEAD;                      // R*4
  float* h1   = tab2 + NREL * NHEAD;                      // N*64
  int* ip = (int*)(h1 + (size_t)N_NODES * 64);
  int* deg     = ip;                                      // N
  int* rowptr  = deg + N_NODES;                           // N+1
  int* cursor  = rowptr + N_NODES + 1;                    // N
  int2* csr    = (int2*)(cursor + N_NODES + 1);           // E int2
  int* bsum    = (int*)(csr + N_EDGES);                   // 256
  int* boff    = bsum + 256;                              // 256

  // ---- CSR build + both alpha_e tables (independent of layers) ----
  hipMemsetAsync(deg, 0, N_NODES * sizeof(int), stream);
  hist_kernel<<<(N_EDGES + 255) / 256, 256, 0, stream>>>(dst, deg);
  block_sum_kernel<<<SCAN_B, 256, 0, stream>>>(deg, bsum);
  scan_bsum_kernel<<<1, 256, 0, stream>>>(bsum, boff);
  scan_final_kernel<<<SCAN_B, 256, 0, stream>>>(deg, boff, rowptr, cursor);
  fill_kernel<<<(N_EDGES + 255) / 256, 256, 0, stream>>>(src, dst, etype, cursor, csr);
  relalpha2_kernel<<<2 * NREL, 256, 0, stream>>>(rel1, We1, ae1, rel2, We2, ae2, tab1, tab2);

  const dim3 gemm_grid((N_NODES + 127) / 128, 2);
  const int GB = (N_NODES * 64 + 255) / 256;   // one wave per node

  // ================= layer 1 =================
  gemm_xw_alpha<<<gemm_grid, 256, 0, stream>>>(x, W1, as1, ad1, xs16, asrc, adst, N_NODES, IN_DIM);
  gat_node_kernel<<<GB, 256, 0, stream>>>(rowptr, csr, asrc, adst, tab1, xs16, b1, h1, 1);

  // ================= layer 2 =================
  gemm_xw_alpha<<<gemm_grid, 256, 0, stream>>>(h1, W2, as2, ad2, xs16, asrc, adst, N_NODES, 64);
  gat_node_kernel<<<GB, 256, 0, stream>>>(rowptr, csr, asrc, adst, tab2, xs16, b2, (float*)d_out, 0);
}